// Round 14
// baseline (679.209 us; speedup 1.0000x reference)
//
#include <hip/hip_runtime.h>

#define B_   2
#define S_   1024
#define D_   4096
#define HQ_  32
#define HKV_ 8
#define HD_  128
#define SCALE_ 0.08838834764831845f

typedef unsigned short u16;
typedef __attribute__((ext_vector_type(8))) short s16x8;
typedef __attribute__((ext_vector_type(4))) short s16x4;
typedef __attribute__((ext_vector_type(4))) float f32x4;

#define MFMA(a,b,c) __builtin_amdgcn_mfma_f32_16x16x32_bf16((a),(b),(c),0,0,0)

__device__ __forceinline__ u16 bf16_rne(float x) {
  unsigned u = __float_as_uint(x);
  u += 0x7fffu + ((u >> 16) & 1u);
  return (u16)(u >> 16);
}
__device__ __forceinline__ float bf16_up(u16 h) {
  return __uint_as_float(((unsigned)h) << 16);
}
__device__ __forceinline__ void split2(float x, u16& h, u16& l) {
  h = bf16_rne(x);
  l = bf16_rne(x - bf16_up(h));
}

// packed hi/lo split (RNE, identical to split2; validated rounds 3-13)
__device__ __forceinline__ void cvt_hi_lo(float a, float b, unsigned& hi, unsigned& lo) {
  unsigned h, l;
  asm("v_cvt_pk_bf16_f32 %0, %1, %2" : "=v"(h) : "v"(a), "v"(b));
  float ra = __uint_as_float(h << 16);
  float rb = __uint_as_float(h & 0xffff0000u);
  float la = a - ra, lb = b - rb;
  asm("v_cvt_pk_bf16_f32 %0, %1, %2" : "=v"(l) : "v"(la), "v"(lb));
  hi = h; lo = l;
}
__device__ __forceinline__ void pack8(float4 x, float4 y, uint4& h, uint4& l) {
  unsigned h0,h1,h2,h3,l0,l1,l2,l3;
  cvt_hi_lo(x.x, x.y, h0, l0);
  cvt_hi_lo(x.z, x.w, h1, l1);
  cvt_hi_lo(y.x, y.y, h2, l2);
  cvt_hi_lo(y.z, y.w, h3, l3);
  h = make_uint4(h0,h1,h2,h3); l = make_uint4(l0,l1,l2,l3);
}

typedef const __attribute__((address_space(1))) void* gas_ptr;
typedef __attribute__((address_space(3))) void* las_ptr;
__device__ __forceinline__ void gload_lds16(const void* g, void* l) {
  __builtin_amdgcn_global_load_lds((gas_ptr)g, (las_ptr)l, 16, 0, 0);
}

// ===========================================================================
// frag_b2: weights (K x N fp32) -> [kt64][nt-global][kk2][512] (pack-converted)
// ===========================================================================
__global__ __launch_bounds__(256) void frag_b2(
    const float* __restrict__ W, u16* __restrict__ dh, u16* __restrict__ dl,
    int N, int n0, int Ntot16, int ntoff)
{
  __shared__ float T[32][68];
  const int kt = blockIdx.x, nbk = blockIdx.y;
  const int tid = threadIdx.x;
#pragma unroll
  for (int rep = 0; rep < 2; ++rep) {
    int idx = tid + rep * 256;
    int row = idx >> 4, c4 = (idx & 15) * 4;
    float4 v = *reinterpret_cast<const float4*>(&W[(size_t)(kt*32 + row) * N + n0 + nbk*64 + c4]);
    *reinterpret_cast<float4*>(&T[row][c4]) = v;
  }
  __syncthreads();
  int c = tid;
  int nt = c >> 6, l = c & 63;
  const size_t base = (((size_t)(kt >> 1) * Ntot16 + ntoff + nbk*4 + nt) * 2 + (kt & 1)) * 512;
  const int r0 = (l >> 4) * 8, cc = nt*16 + (l & 15);
  unsigned hh4[4], ll4[4];
#pragma unroll
  for (int p = 0; p < 4; ++p)
    cvt_hi_lo(T[r0 + 2*p][cc], T[r0 + 2*p + 1][cc], hh4[p], ll4[p]);
  *reinterpret_cast<uint4*>(&dh[base + (size_t)l * 8]) = make_uint4(hh4[0],hh4[1],hh4[2],hh4[3]);
  *reinterpret_cast<uint4*>(&dl[base + (size_t)l * 8]) = make_uint4(ll4[0],ll4[1],ll4[2],ll4[3]);
}

// ===========================================================================
// frag_a: A (M x 4096 fp32) -> [kt64][mt 128][kk2][512] (pack-converted)
// ===========================================================================
__global__ __launch_bounds__(256) void frag_a(
    const float* __restrict__ src, u16* __restrict__ dh, u16* __restrict__ dl)
{
  __shared__ float T[128][68];
  const int kt = blockIdx.x;
  const int mb = blockIdx.y;
  const int tid = threadIdx.x;
#pragma unroll
  for (int rep = 0; rep < 8; ++rep) {
    int idx = tid + rep * 256;
    int row = idx >> 4, c4 = (idx & 15) * 4;
    float4 v = *reinterpret_cast<const float4*>(&src[(size_t)(mb*128 + row) * 4096 + kt*64 + c4]);
    *reinterpret_cast<float4*>(&T[row][c4]) = v;
  }
  __syncthreads();
#pragma unroll
  for (int rep = 0; rep < 4; ++rep) {
    int c = tid + rep * 256;
    int mt = c >> 7, rem = c & 127, kk = rem >> 6, l = rem & 63;
    const int rr = mt*16 + (l & 15), c0 = kk*32 + (l >> 4)*8;
    unsigned hh4[4], ll4[4];
#pragma unroll
    for (int p = 0; p < 4; ++p)
      cvt_hi_lo(T[rr][c0 + 2*p], T[rr][c0 + 2*p + 1], hh4[p], ll4[p]);
    size_t off = (((size_t)(kt*128 + mb*8 + mt)) * 2 + kk) * 512 + (size_t)l * 8;
    *reinterpret_cast<uint4*>(&dh[off]) = make_uint4(hh4[0],hh4[1],hh4[2],hh4[3]);
    *reinterpret_cast<uint4*>(&dl[off]) = make_uint4(ll4[0],ll4[1],ll4[2],ll4[3]);
  }
}

// ===========================================================================
// gemm128_core<NF,RQ> (round-13 verified): hoisted staging, 3 hi/lo passes.
// ===========================================================================
template<int NF, bool RQ>
__device__ __forceinline__ void gemm128_core(
    const u16* __restrict__ PAh, const u16* __restrict__ PAl,
    const u16* __restrict__ PBh, const u16* __restrict__ PBl,
    float* __restrict__ C0, float* __restrict__ C1, float* __restrict__ C2,
    int ldc0, int Nt16, int mb, int nb, u16* L)
{
  const int tid  = threadIdx.x;
  const int lane = tid & 63;
  const int wid  = tid >> 6;
  const int loff = lane * 8;
  const int wm4  = (wid >> 2) * 4;
  const int wnf  = (wid & 3) * NF;
  constexpr int BNT  = 4 * NF;
  constexpr int NCHW = 2 + NF;

  u16* A0 = L;
  u16* A1 = L + 8192;
  u16* B0 = L + 16384;
  u16* B1 = L + 16384 + BNT*1024;

  f32x4 acc[4][NF];
#pragma unroll
  for (int i = 0; i < 4; ++i)
#pragma unroll
    for (int j = 0; j < NF; ++j) acc[i][j] = (f32x4){0.f,0.f,0.f,0.f};

  const u16* sp[NCHW];
  int   dlo[NCHW];
  int   dadd[NCHW];
  size_t adv2[NCHW];
  const size_t aSlab = 131072;
  const size_t bSlab = (size_t)Nt16 * 1024;
#pragma unroll
  for (int i = 0; i < NCHW; ++i) {
    int c = wid + 8*i;
    if (c < 8) {
      sp[i]  = PAh + (size_t)(mb*8 + c)*1024 + loff;
      dlo[i] = c*512;             dadd[i] = 8192;      adv2[i] = aSlab - 512;
    } else if (c < 16) {
      int m = c - 8;
      sp[i]  = PAl + (size_t)(mb*8 + m)*1024 + loff;
      dlo[i] = 4096 + m*512;      dadd[i] = 8192;      adv2[i] = aSlab - 512;
    } else if (c < 16 + BNT) {
      int n = c - 16;
      sp[i]  = PBh + (size_t)(nb*BNT + n)*1024 + loff;
      dlo[i] = 16384 + n*512;     dadd[i] = BNT*1024;  adv2[i] = bSlab - 512;
    } else {
      int n = c - 16 - BNT;
      sp[i]  = PBl + (size_t)(nb*BNT + n)*1024 + loff;
      dlo[i] = 16384 + BNT*512 + n*512; dadd[i] = BNT*1024; adv2[i] = bSlab - 512;
    }
  }

#pragma unroll
  for (int i = 0; i < NCHW; ++i) {
    gload_lds16(sp[i], L + dlo[i]);
    sp[i] += 512;
  }
  __syncthreads();

  for (int t = 0; t < 128; ++t) {
    u16* la = (t & 1) ? A1 : A0;
    u16* lb = (t & 1) ? B1 : B0;
    if (t < 127) {
      const int p = (t + 1) & 1;
#pragma unroll
      for (int i = 0; i < NCHW; ++i) {
        gload_lds16(sp[i], L + dlo[i] + (p ? dadd[i] : 0));
        sp[i] += p ? adv2[i] : 512;
      }
    }

    s16x8 ah[4], al[4], bh[NF], bl[NF];
#pragma unroll
    for (int mf = 0; mf < 4; ++mf)
      ah[mf] = *reinterpret_cast<const s16x8*>(&la[(wm4+mf)*512 + loff]);
#pragma unroll
    for (int nf = 0; nf < NF; ++nf)
      bh[nf] = *reinterpret_cast<const s16x8*>(&lb[(wnf+nf)*512 + loff]);
    __builtin_amdgcn_s_setprio(1);
#pragma unroll
    for (int nf = 0; nf < NF; ++nf)
#pragma unroll
      for (int mf = 0; mf < 4; ++mf)
        acc[mf][nf] = MFMA(ah[mf], bh[nf], acc[mf][nf]);
    __builtin_amdgcn_s_setprio(0);
#pragma unroll
    for (int mf = 0; mf < 4; ++mf)
      al[mf] = *reinterpret_cast<const s16x8*>(&la[4096 + (wm4+mf)*512 + loff]);
    __builtin_amdgcn_s_setprio(1);
#pragma unroll
    for (int nf = 0; nf < NF; ++nf)
#pragma unroll
      for (int mf = 0; mf < 4; ++mf)
        acc[mf][nf] = MFMA(al[mf], bh[nf], acc[mf][nf]);
    __builtin_amdgcn_s_setprio(0);
#pragma unroll
    for (int nf = 0; nf < NF; ++nf)
      bl[nf] = *reinterpret_cast<const s16x8*>(&lb[BNT*512 + (wnf+nf)*512 + loff]);
    __builtin_amdgcn_s_setprio(1);
#pragma unroll
    for (int nf = 0; nf < NF; ++nf)
#pragma unroll
      for (int mf = 0; mf < 4; ++mf)
        acc[mf][nf] = MFMA(ah[mf], bl[nf], acc[mf][nf]);
    __builtin_amdgcn_s_setprio(0);
    __syncthreads();
  }

  const int lg = lane >> 4, lr = lane & 15;
  const int rowb = mb*128 + (wid >> 2) * 64;
#pragma unroll
  for (int mf = 0; mf < 4; ++mf)
#pragma unroll
    for (int nf = 0; nf < NF; ++nf)
#pragma unroll
      for (int r = 0; r < 4; ++r) {
        int row = rowb + mf*16 + lg*4 + r;
        float v = acc[mf][nf][r];
        int gcol = nb*(NF*64) + (wid & 3)*(NF*16) + nf*16 + lr;
        if constexpr (RQ) {
          if (gcol < 4096)      C0[(size_t)row * 4096 + gcol] = v;
          else if (gcol < 5120) C1[(size_t)row * 1024 + (gcol - 4096)] = v;
          else                  C2[(size_t)row * 1024 + (gcol - 5120)] = v;
        } else {
          C0[(size_t)row * ldc0 + gcol] = v;
        }
      }
}

__global__ __launch_bounds__(512, 4) void gemm_qkv3(
    const u16* __restrict__ XAh, const u16* __restrict__ XAl,
    const u16* __restrict__ WBh, const u16* __restrict__ WBl,
    float* __restrict__ qb, float* __restrict__ kb, float* __restrict__ vb)
{
  __shared__ __attribute__((aligned(16))) u16 L[40960];
  int id = blockIdx.x;
  int xcd = id & 7, c = id >> 3;
  int nb = xcd * 4 + (c >> 4);
  int mb = c & 15;
  gemm128_core<3, true>(XAh, XAl, WBh, WBl, qb, kb, vb, 0, 384, mb, nb, L);
}

__global__ __launch_bounds__(512, 4) void gemm_out3(
    const u16* __restrict__ ABh, const u16* __restrict__ ABl,
    const u16* __restrict__ WOh, const u16* __restrict__ WOl,
    float* __restrict__ outp)
{
  __shared__ __attribute__((aligned(16))) u16 L[32768];
  int id = blockIdx.x;
  int xcd = id & 7, c = id >> 3;
  int nb = xcd * 4 + (c >> 4);
  int mb = c & 15;
  gemm128_core<2, false>(ABh, ABl, WOh, WOl, outp, nullptr, nullptr,
                         4096, 256, mb, nb, L);
}

// ===========================================================================
// gemm256_core (round-10 verified) — fallback tier only.
// ===========================================================================
template<int NF, bool RQ>
__device__ __forceinline__ void gemm256_core(
    const u16* __restrict__ PAh, const u16* __restrict__ PAl,
    const u16* __restrict__ PBh, const u16* __restrict__ PBl,
    float* __restrict__ C0, float* __restrict__ C1, float* __restrict__ C2,
    int ldc0, int Nt16, int mb, int nb, int k0, int nk, u16* L)
{
  const int tid  = threadIdx.x;
  const int lane = tid & 63;
  const int wid  = tid >> 6;
  const int loff = lane * 8;
  const int wm8  = (wid >> 2) * 8;
  const int wnf  = (wid & 3) * NF;

  u16* A0 = L;
  u16* A1 = L + 16384;
  u16* B0 = L + 32768;
  u16* B1 = L + 32768 + NF*4096;

  f32x4 acc[8][NF];
#pragma unroll
  for (int i = 0; i < 8; ++i)
#pragma unroll
    for (int j = 0; j < NF; ++j) acc[i][j] = (f32x4){0.f,0.f,0.f,0.f};

  auto STAGE = [&](int t, u16* la_, u16* lb_) {
    const int kt64 = t >> 1, kk = t & 1;
    const size_t aSlab = (size_t)kt64 * 131072;
    const size_t bSlab = (size_t)kt64 * ((size_t)Nt16 * 1024);
    const int NCH = 32 + 8*NF;
#pragma unroll
    for (int c = wid; c < NCH; c += 8) {
      const u16* src; u16* dst;
      if (c < 16) {
        src = PAh + aSlab + (((size_t)(mb*16 + c))*2 + kk)*512;
        dst = la_ + c*512;
      } else if (c < 32) {
        int m = c - 16;
        src = PAl + aSlab + (((size_t)(mb*16 + m))*2 + kk)*512;
        dst = la_ + 8192 + m*512;
      } else if (c < 32 + 4*NF) {
        int n = c - 32;
        src = PBh + bSlab + (((size_t)(nb*4*NF + n))*2 + kk)*512;
        dst = lb_ + n*512;
      } else {
        int n = c - 32 - 4*NF;
        src = PBl + bSlab + (((size_t)(nb*4*NF + n))*2 + kk)*512;
        dst = lb_ + NF*2048 + n*512;
      }
      gload_lds16(src + loff, dst);
    }
  };

  STAGE(k0, (k0 & 1) ? A1 : A0, (k0 & 1) ? B1 : B0);
  __syncthreads();

  for (int t = k0; t < k0 + nk; ++t) {
    u16* la = (t & 1) ? A1 : A0;
    u16* lb = (t & 1) ? B1 : B0;
    if (t + 1 < k0 + nk)
      STAGE(t + 1, (t & 1) ? A0 : A1, (t & 1) ? B0 : B1);

    s16x8 ah[8], al[8], bh[NF], bl[NF];
#pragma unroll
    for (int mf = 0; mf < 8; ++mf)
      ah[mf] = *reinterpret_cast<const s16x8*>(&la[(wm8+mf)*512 + loff]);
#pragma unroll
    for (int nf = 0; nf < NF; ++nf)
      bh[nf] = *reinterpret_cast<const s16x8*>(&lb[(wnf+nf)*512 + loff]);
    __builtin_amdgcn_s_setprio(1);
#pragma unroll
    for (int nf = 0; nf < NF; ++nf)
#pragma unroll
      for (int mf = 0; mf < 8; ++mf)
        acc[mf][nf] = MFMA(ah[mf], bh[nf], acc[mf][nf]);
    __builtin_amdgcn_s_setprio(0);
#pragma unroll
    for (int mf = 0; mf < 8; ++mf)
      al[mf] = *reinterpret_cast<const s16x8*>(&la[8192 + (wm8+mf)*512 + loff]);
    __builtin_amdgcn_s_setprio(1);
#pragma unroll
    for (int nf = 0; nf < NF; ++nf)
#pragma unroll
      for (int mf = 0; mf < 8; ++mf)
        acc[mf][nf] = MFMA(al[mf], bh[nf], acc[mf][nf]);
    __builtin_amdgcn_s_setprio(0);
#pragma unroll
    for (int nf = 0; nf < NF; ++nf)
      bl[nf] = *reinterpret_cast<const s16x8*>(&lb[NF*2048 + (wnf+nf)*512 + loff]);
    __builtin_amdgcn_s_setprio(1);
#pragma unroll
    for (int nf = 0; nf < NF; ++nf)
#pragma unroll
      for (int mf = 0; mf < 8; ++mf)
        acc[mf][nf] = MFMA(ah[mf], bl[nf], acc[mf][nf]);
    __builtin_amdgcn_s_setprio(0);
    __syncthreads();
  }

  const int lg = lane >> 4, lr = lane & 15;
  const int rowb = mb*256 + (wid >> 2) * 128;
#pragma unroll
  for (int mf = 0; mf < 8; ++mf)
#pragma unroll
    for (int nf = 0; nf < NF; ++nf)
#pragma unroll
      for (int r = 0; r < 4; ++r) {
        int row = rowb + mf*16 + lg*4 + r;
        float v = acc[mf][nf][r];
        if constexpr (RQ) {
          int gcol = nb*(NF*64) + (wid & 3)*(NF*16) + nf*16 + lr;
          if (gcol < 4096)      C0[(size_t)row * 4096 + gcol] = v;
          else if (gcol < 5120) C1[(size_t)row * 1024 + (gcol - 4096)] = v;
          else                  C2[(size_t)row * 1024 + (gcol - 5120)] = v;
        } else {
          int col = nb*(NF*64) + (wid & 3)*(NF*16) + nf*16 + lr;
          C0[(size_t)row * ldc0 + col] = v;
        }
      }
}

__global__ __launch_bounds__(512) void gemm_qkv2(
    const u16* __restrict__ XAh, const u16* __restrict__ XAl,
    const u16* __restrict__ WA,
    float* __restrict__ qb, float* __restrict__ kb, float* __restrict__ vb)
{
  __shared__ __attribute__((aligned(16))) u16 L[65536];
  int id = blockIdx.x;
  int swz = (id & 7) * 24 + (id >> 3);
  const u16 *Bh, *Bl; float* C; int ldc, Nt16, mb, nb;
  if (swz < 128)      { Bh = WA;          Bl = WA+16777216; C = qb; ldc = 4096; Nt16 = 256; mb = swz & 7;  nb = swz >> 3; }
  else if (swz < 160) { int u = swz-128; Bh = WA+33554432; Bl = WA+37748736; C = kb; ldc = 1024; Nt16 = 64; mb = u & 7; nb = u >> 3; }
  else                { int u = swz-160; Bh = WA+41943040; Bl = WA+46137344; C = vb; ldc = 1024; Nt16 = 64; mb = u & 7; nb = u >> 3; }
  gemm256_core<4, false>(XAh, XAl, Bh, Bl, C, nullptr, nullptr, ldc, Nt16, mb, nb, 0, 128, L);
}

__global__ __launch_bounds__(512) void gemm_out2(
    const u16* __restrict__ ABh, const u16* __restrict__ ABl,
    const u16* __restrict__ WOh, const u16* __restrict__ WOl,
    float* __restrict__ outp, float* __restrict__ c2)
{
  __shared__ __attribute__((aligned(16))) u16 L[65536];
  int id = blockIdx.x;
  int swz = (id & 7) * 32 + (id >> 3);
  int u = swz & 127, s = swz >> 7;
  int mb = u & 7, nb = u >> 3;
  gemm256_core<4, false>(ABh, ABl, WOh, WOl, s ? c2 : outp, nullptr, nullptr,
                         4096, 256, mb, nb, s*64, 64, L);
}

__global__ __launch_bounds__(256) void add_out(
    float* __restrict__ o, const float* __restrict__ c2)
{
  int i = blockIdx.x * 256 + threadIdx.x;
  float4 a = reinterpret_cast<float4*>(o)[i];
  float4 b = reinterpret_cast<const float4*>(c2)[i];
  a.x += b.x; a.y += b.y; a.z += b.z; a.w += b.w;
  reinterpret_cast<float4*>(o)[i] = a;
}

// ===========================================================================
// frag_kv: post-GEMM K,V -> fragment planes, K-RoPE fused (pack-converted).
// ===========================================================================
__global__ __launch_bounds__(256) void frag_kv(
    const float* __restrict__ kb, const float* __restrict__ vb,
    const float* __restrict__ cosT, const float* __restrict__ sinT,
    u16* __restrict__ KFh, u16* __restrict__ KFl,
    u16* __restrict__ VFh, u16* __restrict__ VFl)
{
  __shared__ float T[32][132];
  const int bid  = blockIdx.x;
  const int isV  = bid >> 9;
  const int bkvh = (bid >> 5) & 15;
  const int chnk = bid & 31;
  const int tid  = threadIdx.x;
  const int b    = bkvh >> 3, kvh = bkvh & 7;

  const float* src = isV ? vb : kb;
  {
    int r0 = tid >> 5, c4 = (tid & 31) * 4;
    float sgn = (c4 < 64) ? -1.f : 1.f;
#pragma unroll
    for (int it = 0; it < 4; ++it) {
      int row = r0 + it * 8;
      int srow = chnk*32 + row;
      const float* rp = &src[(((size_t)(b * S_ + srow)) * HKV_ + kvh) * HD_];
      float4 v = *reinterpret_cast<const float4*>(rp + c4);
      if (!isV) {
        float4 p  = *reinterpret_cast<const float4*>(rp + (c4 ^ 64));
        float4 cc = *reinterpret_cast<const float4*>(&cosT[((size_t)(b*S_ + srow))*HD_ + c4]);
        float4 ss = *reinterpret_cast<const float4*>(&sinT[((size_t)(b*S_ + srow))*HD_ + c4]);
        v.x = v.x*cc.x + sgn*p.x*ss.x;
        v.y = v.y*cc.y + sgn*p.y*ss.y;
        v.z = v.z*cc.z + sgn*p.z*ss.z;
        v.w = v.w*cc.w + sgn*p.w*ss.w;
      }
      *reinterpret_cast<float4*>(&T[row][c4]) = v;
    }
  }
  __syncthreads();
#pragma unroll
  for (int rep = 0; rep < 2; ++rep) {
    int c2 = tid + rep * 256;
    int l = c2 & 63;
    unsigned hh4[4], ll4[4];
    if (!isV) {
      int f = c2 >> 6, st_loc = f >> 2, dt = f & 3;
      const int rr = st_loc*16 + (l & 15), c0 = dt*32 + (l >> 4)*8;
#pragma unroll
      for (int p = 0; p < 4; ++p)
        cvt_hi_lo(T[rr][c0 + 2*p], T[rr][c0 + 2*p + 1], hh4[p], ll4[p]);
      size_t off = ((size_t)bkvh*64 + chnk*2) * 2048 + (size_t)c2 * 8;
      *reinterpret_cast<uint4*>(&KFh[off]) = make_uint4(hh4[0],hh4[1],hh4[2],hh4[3]);
      *reinterpret_cast<uint4*>(&KFl[off]) = make_uint4(ll4[0],ll4[1],ll4[2],ll4[3]);
    } else {
      int dt16 = c2 >> 6;
      const int r0 = (l >> 4)*8, cc = dt16*16 + (l & 15);
#pragma unroll
      for (int p = 0; p < 4; ++p)
        cvt_hi_lo(T[r0 + 2*p][cc], T[r0 + 2*p + 1][cc], hh4[p], ll4[p]);
      size_t off = ((size_t)bkvh*32 + chnk) * 4096 + (size_t)c2 * 8;
      *reinterpret_cast<uint4*>(&VFh[off]) = make_uint4(hh4[0],hh4[1],hh4[2],hh4[3]);
      *reinterpret_cast<uint4*>(&VFl[off]) = make_uint4(ll4[0],ll4[1],ll4[2],ll4[3]);
    }
  }
}

// ===========================================================================
// attn4 (NEW, main tier): KVBLK=32, 4-wave blocks (QBLK=64), LDS 41KB ->
// 3 blocks/CU co-residency. Same verified flash structure as attn3.
// grid (16 qt, 64 bh), 256 thr.
// ===========================================================================
__global__ __launch_bounds__(256, 3) void attn4(
    const float* __restrict__ qb,
    const float* __restrict__ cosT, const float* __restrict__ sinT,
    const u16* __restrict__ KFh, const u16* __restrict__ KFl,
    const u16* __restrict__ VFh, const u16* __restrict__ VFl,
    float* __restrict__ ob)
{
  __shared__ __attribute__((aligned(16))) u16 Klds[8192];  // hi @0, lo @4096
  __shared__ __attribute__((aligned(16))) u16 Vlds[8192];
  __shared__ u16 Ph[4][16][36], Pl[4][16][36];

  const int tid  = threadIdx.x;
  const int lane = tid & 63;
  const int wid  = tid >> 6;          // 0..3
  const int lr   = lane & 15;
  const int lg   = lane >> 4;
  const int loff = lane * 8;
  const int qt   = blockIdx.x;        // 0..15
  const int bh   = blockIdx.y;
  const int b    = bh >> 5, h = bh & 31;
  const int bkvh = b * 8 + (h >> 2);

  // ---- Q rows -> A-fragments with fused RoPE ----
  s16x8 qh[4], ql[4];
  {
    const int qrow = qt * 64 + wid * 16 + lr;
    const float* qp = qb + ((size_t)((b * S_ + qrow) * HQ_ + h)) * HD_;
    const float* cp = cosT + ((size_t)(b * S_ + qrow)) * HD_;
    const float* sp = sinT + ((size_t)(b * S_ + qrow)) * HD_;
#pragma unroll
    for (int kc = 0; kc < 4; ++kc) {
      const int d0 = kc * 32 + lg * 8;
      const float sgn = (d0 < 64) ? -1.f : 1.f;
      float4 v0 = *reinterpret_cast<const float4*>(qp + d0);
      float4 v1 = *reinterpret_cast<const float4*>(qp + d0 + 4);
      float4 p0 = *reinterpret_cast<const float4*>(qp + (d0 ^ 64));
      float4 p1 = *reinterpret_cast<const float4*>(qp + (d0 ^ 64) + 4);
      float4 c0 = *reinterpret_cast<const float4*>(cp + d0);
      float4 c1 = *reinterpret_cast<const float4*>(cp + d0 + 4);
      float4 s0 = *reinterpret_cast<const float4*>(sp + d0);
      float4 s1 = *reinterpret_cast<const float4*>(sp + d0 + 4);
      float4 r0, r1;
      r0.x = v0.x*c0.x + sgn*p0.x*s0.x;  r0.y = v0.y*c0.y + sgn*p0.y*s0.y;
      r0.z = v0.z*c0.z + sgn*p0.z*s0.z;  r0.w = v0.w*c0.w + sgn*p0.w*s0.w;
      r1.x = v1.x*c1.x + sgn*p1.x*s1.x;  r1.y = v1.y*c1.y + sgn*p1.y*s1.y;
      r1.z = v1.z*c1.z + sgn*p1.z*s1.z;  r1.w = v1.w*c1.w + sgn*p1.w*s1.w;
      uint4 h4, l4; pack8(r0, r1, h4, l4);
      qh[kc] = *reinterpret_cast<s16x8*>(&h4);
      ql[kc] = *reinterpret_cast<s16x8*>(&l4);
    }
  }

  f32x4 acc_o[8];
#pragma unroll
  for (int df = 0; df < 8; ++df) acc_o[df] = (f32x4){0.f, 0.f, 0.f, 0.f};
  float m_run[4] = {-1e30f, -1e30f, -1e30f, -1e30f};
  float l_run[4] = {0.f, 0.f, 0.f, 0.f};

  const u16* gKh = KFh + (size_t)bkvh * 131072;
  const u16* gKl = KFl + (size_t)bkvh * 131072;
  const u16* gVh = VFh + (size_t)bkvh * 131072;
  const u16* gVl = VFl + (size_t)bkvh * 131072;

  // prologue: stage K(0) — 16 chunks over 4 waves (2 hi + 2 lo each)
#pragma unroll
  for (int i = 0; i < 2; ++i) {
    int c = wid * 2 + i;               // 0..7
    gload_lds16(gKh + c*512 + loff, Klds + c*512);
    gload_lds16(gKl + c*512 + loff, Klds + 4096 + c*512);
  }
  __syncthreads();

  for (int t = 0; t < 32; ++t) {
    // stage V(t)
#pragma unroll
    for (int i = 0; i < 2; ++i) {
      int c = wid * 2 + i;
      gload_lds16(gVh + t*4096 + c*512 + loff, Vlds + c*512);
      gload_lds16(gVl + t*4096 + c*512 + loff, Vlds + 4096 + c*512);
    }

    // ---- QK^T: 16 x 32 per wave ----
    f32x4 accs[2];
#pragma unroll
    for (int nf = 0; nf < 2; ++nf) {
      accs[nf] = (f32x4){0.f, 0.f, 0.f, 0.f};
      s16x8 kh8[4], kl8[4];
#pragma unroll
      for (int kc = 0; kc < 4; ++kc) {
        kh8[kc] = *reinterpret_cast<const s16x8*>(&Klds[nf*2048 + kc*512 + loff]);
        kl8[kc] = *reinterpret_cast<const s16x8*>(&Klds[4096 + nf*2048 + kc*512 + loff]);
      }
#pragma unroll
      for (int kc = 0; kc < 4; ++kc) {
        accs[nf] = MFMA(qh[kc], kh8[kc], accs[nf]);
        accs[nf] = MFMA(ql[kc], kh8[kc], accs[nf]);
        accs[nf] = MFMA(qh[kc], kl8[kc], accs[nf]);
      }
    }
#pragma unroll
    for (int nf = 0; nf < 2; ++nf) accs[nf] *= SCALE_;

    // ---- online softmax ----
    float corr[4], rsum[4];
#pragma unroll
    for (int r = 0; r < 4; ++r) {
      float t0 = fmaxf(accs[0][r], accs[1][r]);
      t0 = fmaxf(t0, __shfl_xor(t0, 1));
      t0 = fmaxf(t0, __shfl_xor(t0, 2));
      t0 = fmaxf(t0, __shfl_xor(t0, 4));
      t0 = fmaxf(t0, __shfl_xor(t0, 8));
      float mnew = fmaxf(m_run[r], t0);
      corr[r] = __expf(m_run[r] - mnew);
      m_run[r] = mnew;
      rsum[r] = 0.f;
    }
#pragma unroll
    for (int nf = 0; nf < 2; ++nf)
#pragma unroll
      for (int r = 0; r < 4; ++r) {
        float p = __expf(accs[nf][r] - m_run[r]);
        rsum[r] += p;
        u16 ph, pl;
        split2(p, ph, pl);
        Ph[wid][lg*4 + r][nf*16 + lr] = ph;
        Pl[wid][lg*4 + r][nf*16 + lr] = pl;
      }
#pragma unroll
    for (int r = 0; r < 4; ++r) {
      float s = rsum[r];
      s += __shfl_xor(s, 1); s += __shfl_xor(s, 2);
      s += __shfl_xor(s, 4); s += __shfl_xor(s, 8);
      l_run[r] = l_run[r] * corr[r] + s;
    }
#pragma unroll
    for (int df = 0; df < 8; ++df)
#pragma unroll
      for (int r = 0; r < 4; ++r) acc_o[df][r] *= corr[r];

    __syncthreads();   // V(t) staged; all waves done reading Klds

    // stage K(t+1)
    if (t < 31) {
#pragma unroll
      for (int i = 0; i < 2; ++i) {
        int c = wid * 2 + i;
        gload_lds16(gKh + (t+1)*4096 + c*512 + loff, Klds + c*512);
        gload_lds16(gKl + (t+1)*4096 + c*512 + loff, Klds + 4096 + c*512);
      }
    }

    // ---- PV: P(16x32) x V(32x128) ----
    s16x8 pa_h = *reinterpret_cast<const s16x8*>(&Ph[wid][lr][lg*8]);
    s16x8 pa_l = *reinterpret_cast<const s16x8*>(&Pl[wid][lr][lg*8]);
#pragma unroll
    for (int df = 0; df < 8; ++df) {
      s16x8 vh8 = *reinterpret_cast<const s16x8*>(&Vlds[df*512 + loff]);
      s16x8 vl8 = *reinterpret_cast<const s16x8*>(&Vlds[4096 + df*512 + loff]);
      acc_o[df] = MFMA(pa_h, vh8, acc_o[df]);
      acc_o[df] = MFMA(pa_l, vh8, acc_o[df]);
      acc_o[df] = MFMA(pa_h, vl8, acc_o[df]);
    }
    __syncthreads();   // K(t+1) staged; all waves done reading Vlds
  }

  float inv_l[4];
#pragma unroll
  for (int r = 0; r < 4; ++r) inv_l[r] = 1.f / l_run[r];
#pragma unroll
  for (int df = 0; df < 8; ++df)
#pragma unroll
    for (int r = 0; r < 4; ++r) {
      int row = qt * 64 + wid * 16 + lg * 4 + r;
      ob[((size_t)((b * S_ + row) * HQ_ + h)) * HD_ + df*16 + lr] = acc_o[df][r] * inv_l[r];
    }
}

// ===========================================================================
// attn3 (round-13 verified) — fallback tier only.
// ===========================================================================
__global__ __launch_bounds__(512) void attn3(
    const float* __restrict__ qb,
    const float* __restrict__ cosT, const float* __restrict__ sinT,
    const u16* __restrict__ KFh, const u16* __restrict__ KFl,
    const u16* __restrict__ VFh, const u16* __restrict__ VFl,
    float* __restrict__ ob)
{
  __shared__ __attribute__((aligned(16))) u16 Klds[16384];
  __shared__ __attribute__((aligned(16))) u16 Vlds[16384];
  __shared__ u16 Ph[8][16][68], Pl[8][16][68];

  const int tid  = threadIdx.x;
  const int lane = tid & 63;
  const int wid  = tid >> 6;
  const int lr   = lane & 15;
  const int lg   = lane >> 4;
  const int loff = lane * 8;
  const int qt   = blockIdx.x;
  const int bh   = blockIdx.y;
  const int b    = bh >> 5, h = bh & 31;
  const int bkvh = b * 8 + (h >> 2);

  s16x8 qh[4], ql[4];
  {
    const int qrow = qt * 128 + wid * 16 + lr;
    const float* qp = qb + ((size_t)((b * S_ + qrow) * HQ_ + h)) * HD_;
    const float* cp = cosT + ((size_t)(b * S_ + qrow)) * HD_;
    const float* sp = sinT + ((size_t)(b * S_ + qrow)) * HD_;
#pragma unroll
    for (int kc = 0; kc < 4; ++kc) {
      const int d0 = kc * 32 + lg * 8;
      const float sgn = (d0 < 64) ? -1.f : 1.f;
      float4 v0 = *reinterpret_cast<const float4*>(qp + d0);
      float4 v1 = *reinterpret_cast<const float4*>(qp + d0 + 4);
      float4 p0 = *reinterpret_cast<const float4*>(qp + (d0 ^ 64));
      float4 p1 = *reinterpret_cast<const float4*>(qp + (d0 ^ 64) + 4);
      float4 c0 = *reinterpret_cast<const float4*>(cp + d0);
      float4 c1 = *reinterpret_cast<const float4*>(cp + d0 + 4);
      float4 s0 = *reinterpret_cast<const float4*>(sp + d0);
      float4 s1 = *reinterpret_cast<const float4*>(sp + d0 + 4);
      float4 r0, r1;
      r0.x = v0.x*c0.x + sgn*p0.x*s0.x;  r0.y = v0.y*c0.y + sgn*p0.y*s0.y;
      r0.z = v0.z*c0.z + sgn*p0.z*s0.z;  r0.w = v0.w*c0.w + sgn*p0.w*s0.w;
      r1.x = v1.x*c1.x + sgn*p1.x*s1.x;  r1.y = v1.y*c1.y + sgn*p1.y*s1.y;
      r1.z = v1.z*c1.z + sgn*p1.z*s1.z;  r1.w = v1.w*c1.w + sgn*p1.w*s1.w;
      uint4 h4, l4; pack8(r0, r1, h4, l4);
      qh[kc] = *reinterpret_cast<s16x8*>(&h4);
      ql[kc] = *reinterpret_cast<s16x8*>(&l4);
    }
  }

  f32x4 acc_o[8];
#pragma unroll
  for (int df = 0; df < 8; ++df) acc_o[df] = (f32x4){0.f, 0.f, 0.f, 0.f};
  float m_run[4] = {-1e30f, -1e30f, -1e30f, -1e30f};
  float l_run[4] = {0.f, 0.f, 0.f, 0.f};

  const u16* gKh = KFh + (size_t)bkvh * 131072;
  const u16* gKl = KFl + (size_t)bkvh * 131072;
  const u16* gVh = VFh + (size_t)bkvh * 131072;
  const u16* gVl = VFl + (size_t)bkvh * 131072;

#pragma unroll
  for (int i = 0; i < 4; ++i) {
    int idx = wid * 4 + i;
    const u16* src = (idx < 16) ? (gKh + idx*512) : (gKl + (idx-16)*512);
    u16* dst = Klds + ((idx < 16) ? idx*512 : 8192 + (idx-16)*512);
    gload_lds16(src + loff, dst);
  }
  __syncthreads();

  for (int t = 0; t < 16; ++t) {
#pragma unroll
    for (int i = 0; i < 4; ++i) {
      int idx = wid * 4 + i;
      const u16* src = (idx < 16) ? (gVh + t*8192 + idx*512)
                                  : (gVl + t*8192 + (idx-16)*512);
      u16* dst = Vlds + ((idx < 16) ? idx*512 : 8192 + (idx-16)*512);
      gload_lds16(src + loff, dst);
    }

    f32x4 accs[4];
#pragma unroll
    for (int nf = 0; nf < 4; ++nf) {
      accs[nf] = (f32x4){0.f, 0.f, 0.f, 0.f};
      s16x8 kh8[4], kl8[4];
#pragma unroll
      for (int kc = 0; kc < 4; ++kc) {
        kh8[kc] = *reinterpret_cast<const s16x8*>(&Klds[nf*2048 + kc*512 + loff]);
        kl8[kc] = *reinterpret_cast<const s16x8*>(&Klds[8192 + nf*2048 + kc*512 + loff]);
      }
#pragma unroll
      for (int kc = 0; kc < 4; ++kc) {
        accs[nf] = MFMA(qh[kc], kh8[kc], accs[nf]);
        accs[nf] = MFMA(ql[kc], kh8[kc], accs[nf]);
        accs[nf] = MFMA(qh[kc], kl8[kc], accs[nf]);
      }
    }
#pragma unroll
    for (int nf = 0; nf < 4; ++nf) accs[nf] *= SCALE_;

    float corr[4], rsum[4];
#pragma unroll
    for (int r = 0; r < 4; ++r) {
      float t0 = fmaxf(fmaxf(accs[0][r], accs[1][r]), fmaxf(accs[2][r], accs[3][r]));
      t0 = fmaxf(t0, __shfl_xor(t0, 1));
      t0 = fmaxf(t0, __shfl_xor(t0, 2));
      t0 = fmaxf(t0, __shfl_xor(t0, 4));
      t0 = fmaxf(t0, __shfl_xor(t0, 8));
      float mnew = fmaxf(m_run[r], t0);
      corr[r] = __expf(m_run[r] - mnew);
      m_run[r] = mnew;
      rsum[r] = 0.f;
    }
#pragma unroll
    for (int nf = 0; nf < 4; ++nf)
#pragma unroll
      for (int r = 0; r < 4; ++r) {
        float p = __expf(accs[nf][r] - m_run[r]);
        rsum[r] += p;
        u16 ph, pl;
        split2(p, ph, pl);
        Ph[wid][lg*4 + r][nf*16 + lr] = ph;
        Pl[wid][lg*4 + r][nf*16 + lr] = pl;
      }
#pragma unroll
    for (int r = 0; r < 4; ++r) {
      float s = rsum[r];
      s += __shfl_xor(s, 1); s += __shfl_xor(s, 2);
      s += __shfl_xor(s, 4); s += __shfl_xor(s, 8);
      l_run[r] = l_run[r] * corr[r] + s;
    }
#pragma unroll
    for (int df = 0; df < 8; ++df)
#pragma unroll
      for (int r = 0; r < 4; ++r) acc_o[df][r] *= corr[r];

    __syncthreads();

    if (t < 15) {
#pragma unroll
      for (int i = 0; i < 4; ++i) {
        int idx = wid * 4 + i;
        const u16* src = (idx < 16) ? (gKh + (t+1)*8192 + idx*512)
                                    : (gKl + (t+1)*8192 + (idx-16)*512);
        u16* dst = Klds + ((idx < 16) ? idx*512 : 8192 + (idx-16)*512);
        gload_lds16(src + loff, dst);
      }
    }

    s16x8 pa_h[2], pa_l[2];
#pragma unroll
    for (int kc = 0; kc < 2; ++kc) {
      pa_h[kc] = *reinterpret_cast<const s16x8*>(&Ph[wid][lr][kc*32 + lg*8]);
      pa_l[kc] = *reinterpret_cast<const s16x8*>(&Pl[wid][lr][kc*32 + lg*8]);
    }
#pragma unroll
    for (int df = 0; df < 8; ++df) {
      s16x8 vh8[2], vl8[2];
#pragma unroll
      for (int kc = 0; kc < 2; ++kc) {
        vh8[kc] = *reinterpret_cast<const s16x8*>(&Vlds[kc*4096 + df*512 + loff]);
        vl8[kc] = *reinterpret_cast<const s16x8*>(&Vlds[8192 + kc*4096 + df*512 + loff]);
      }
#pragma unroll
      for (int kc = 0; kc < 2; ++kc) {
        acc_o[df] = MFMA(pa_h[kc], vh8[kc], acc_o[df]);
        acc_o[df] = MFMA(pa_l[kc], vh8[kc], acc_o[df]);
        acc_o[df] = MFMA(pa_h[kc], vl8[kc], acc_o[df]);
      }
    }
    __syncthreads();
  }

  float inv_l[4];
#pragma unroll
  for (int r = 0; r < 4; ++r) inv_l[r] = 1.f / l_run[r];
#pragma unroll
  for (int df = 0; df < 8; ++df)
#pragma unroll
    for (int r = 0; r < 4; ++r) {
      int row = qt * 128 + wid * 16 + lg * 4 + r;
      ob[((size_t)((b * S_ + row) * HQ_ + h)) * HD_ + df*16 + lr] = acc_o[df][r] * inv_l[r];
    }
}

// ---------------------------------------------------------------------------
extern "C" void kernel_launch(void* const* d_in, const int* in_sizes, int n_in,
                              void* d_out, int out_size, void* d_ws, size_t ws_size,
                              hipStream_t stream)
{
  const float* hs   = (const float*)d_in[0];
  const float* cosT = (const float*)d_in[1];
  const float* sinT = (const float*)d_in[2];
  const float* Wq   = (const float*)d_in[3];
  const float* Wk   = (const float*)d_in[4];
  const float* Wv   = (const float*)d_in[5];
  const float* Wo   = (const float*)d_in[6];
  float* out = (float*)d_out;

  float* qb = (float*)d_ws;                 // 8388608 f32
  float* kb = qb + 8388608;                 // 2097152
  float* vb = kb + 2097152;                 // 2097152
  float* ab = vb + 2097152;                 // 8388608
  u16*   FR = (u16*)(ab + 8388608);

  const size_t WS212 = 222298112ULL;

  if (ws_size >= WS212) {
    u16* XAh = FR;
    u16* XAl = FR + 8388608;
    u16* WBh = FR + 16777216;
    u16* WBl = FR + 41943040;
    u16* KFh = FR + 16777216;
    u16* KFl = FR + 18874368;
    u16* VFh = FR + 20971520;
    u16* VFl = FR + 23068672;
    u16* WOh = FR + 25165824;
    u16* WOl = FR + 41943040;

    frag_a<<<dim3(64,16), 256, 0, stream>>>(hs, XAh, XAl);
    frag_b2<<<dim3(128,64), 256, 0, stream>>>(Wq, WBh, WBl, 4096, 0, 384, 0);
    frag_b2<<<dim3(128,16), 256, 0, stream>>>(Wk, WBh, WBl, 1024, 0, 384, 256);
    frag_b2<<<dim3(128,16), 256, 0, stream>>>(Wv, WBh, WBl, 1024, 0, 384, 320);
    gemm_qkv3<<<512, 512, 0, stream>>>(XAh, XAl, WBh, WBl, qb, kb, vb);
    frag_kv<<<1024, 256, 0, stream>>>(kb, vb, cosT, sinT, KFh, KFl, VFh, VFl);
    frag_b2<<<dim3(128,64), 256, 0, stream>>>(Wo, WOh, WOl, 4096, 0, 256, 0);
    attn4<<<dim3(16, 64), 256, 0, stream>>>(qb, cosT, sinT, KFh, KFl, VFh, VFl, ab);
    frag_a<<<dim3(64,16), 256, 0, stream>>>(ab, XAh, XAl);
    gemm_out3<<<512, 512, 0, stream>>>(XAh, XAl, WOh, WOl, out);
  } else {
    // round-13 verified fallback (WS208)
    u16* XAh = FR;
    u16* XAl = FR + 8388608;
    u16* WA  = FR + 16777216;
    frag_a<<<dim3(64,16), 256, 0, stream>>>(hs, XAh, XAl);
    frag_b2<<<dim3(128,64), 256, 0, stream>>>(Wq, WA,           WA+16777216, 4096, 0, 256, 0);
    frag_b2<<<dim3(128,16), 256, 0, stream>>>(Wk, WA+33554432,  WA+37748736, 1024, 0, 64, 0);
    frag_b2<<<dim3(128,16), 256, 0, stream>>>(Wv, WA+41943040,  WA+46137344, 1024, 0, 64, 0);
    gemm_qkv2<<<192, 512, 0, stream>>>(XAh, XAl, WA, qb, kb, vb);
    frag_kv<<<1024, 256, 0, stream>>>(kb, vb, cosT, sinT,
                                      WA, WA+2097152, WA+4194304, WA+6291456);
    frag_b2<<<dim3(128,64), 256, 0, stream>>>(Wo, WA+8388608, WA+25165824, 4096, 0, 256, 0);
    attn3<<<dim3(8, 64), 512, 0, stream>>>(qb, cosT, sinT,
                                           WA, WA+2097152, WA+4194304, WA+6291456, ab);
    frag_a<<<dim3(64,16), 256, 0, stream>>>(ab, XAh, XAl);
    gemm_out2<<<256, 512, 0, stream>>>(XAh, XAl, WA+8388608, WA+25165824, out, qb);
    add_out<<<8192, 256, 0, stream>>>(out, qb);
  }
}

// Round 15
// 647.652 us; speedup vs baseline: 1.0487x; 1.0487x over previous
//
#include <hip/hip_runtime.h>

#define B_   2
#define S_   1024
#define D_   4096
#define HQ_  32
#define HKV_ 8
#define HD_  128
#define SCALE_ 0.08838834764831845f

typedef unsigned short u16;
typedef __attribute__((ext_vector_type(8))) short s16x8;
typedef __attribute__((ext_vector_type(4))) short s16x4;
typedef __attribute__((ext_vector_type(4))) float f32x4;

#define MFMA(a,b,c) __builtin_amdgcn_mfma_f32_16x16x32_bf16((a),(b),(c),0,0,0)

__device__ __forceinline__ u16 bf16_rne(float x) {
  unsigned u = __float_as_uint(x);
  u += 0x7fffu + ((u >> 16) & 1u);
  return (u16)(u >> 16);
}
__device__ __forceinline__ float bf16_up(u16 h) {
  return __uint_as_float(((unsigned)h) << 16);
}
__device__ __forceinline__ void split2(float x, u16& h, u16& l) {
  h = bf16_rne(x);
  l = bf16_rne(x - bf16_up(h));
}

// packed hi/lo split (RNE, identical to split2; validated rounds 3-14)
__device__ __forceinline__ void cvt_hi_lo(float a, float b, unsigned& hi, unsigned& lo) {
  unsigned h, l;
  asm("v_cvt_pk_bf16_f32 %0, %1, %2" : "=v"(h) : "v"(a), "v"(b));
  float ra = __uint_as_float(h << 16);
  float rb = __uint_as_float(h & 0xffff0000u);
  float la = a - ra, lb = b - rb;
  asm("v_cvt_pk_bf16_f32 %0, %1, %2" : "=v"(l) : "v"(la), "v"(lb));
  hi = h; lo = l;
}
__device__ __forceinline__ void pack8(float4 x, float4 y, uint4& h, uint4& l) {
  unsigned h0,h1,h2,h3,l0,l1,l2,l3;
  cvt_hi_lo(x.x, x.y, h0, l0);
  cvt_hi_lo(x.z, x.w, h1, l1);
  cvt_hi_lo(y.x, y.y, h2, l2);
  cvt_hi_lo(y.z, y.w, h3, l3);
  h = make_uint4(h0,h1,h2,h3); l = make_uint4(l0,l1,l2,l3);
}

typedef const __attribute__((address_space(1))) void* gas_ptr;
typedef __attribute__((address_space(3))) void* las_ptr;
__device__ __forceinline__ void gload_lds16(const void* g, void* l) {
  __builtin_amdgcn_global_load_lds((gas_ptr)g, (las_ptr)l, 16, 0, 0);
}

// ===========================================================================
// frag_b2: weights (K x N fp32) -> [kt64][nt-global][kk2][512] (pack-converted)
// ===========================================================================
__global__ __launch_bounds__(256) void frag_b2(
    const float* __restrict__ W, u16* __restrict__ dh, u16* __restrict__ dl,
    int N, int n0, int Ntot16, int ntoff)
{
  __shared__ float T[32][68];
  const int kt = blockIdx.x, nbk = blockIdx.y;
  const int tid = threadIdx.x;
#pragma unroll
  for (int rep = 0; rep < 2; ++rep) {
    int idx = tid + rep * 256;
    int row = idx >> 4, c4 = (idx & 15) * 4;
    float4 v = *reinterpret_cast<const float4*>(&W[(size_t)(kt*32 + row) * N + n0 + nbk*64 + c4]);
    *reinterpret_cast<float4*>(&T[row][c4]) = v;
  }
  __syncthreads();
  int c = tid;
  int nt = c >> 6, l = c & 63;
  const size_t base = (((size_t)(kt >> 1) * Ntot16 + ntoff + nbk*4 + nt) * 2 + (kt & 1)) * 512;
  const int r0 = (l >> 4) * 8, cc = nt*16 + (l & 15);
  unsigned hh4[4], ll4[4];
#pragma unroll
  for (int p = 0; p < 4; ++p)
    cvt_hi_lo(T[r0 + 2*p][cc], T[r0 + 2*p + 1][cc], hh4[p], ll4[p]);
  *reinterpret_cast<uint4*>(&dh[base + (size_t)l * 8]) = make_uint4(hh4[0],hh4[1],hh4[2],hh4[3]);
  *reinterpret_cast<uint4*>(&dl[base + (size_t)l * 8]) = make_uint4(ll4[0],ll4[1],ll4[2],ll4[3]);
}

// ===========================================================================
// frag_a: A (M x 4096 fp32) -> [kt64][mt 128][kk2][512] (pack-converted)
// ===========================================================================
__global__ __launch_bounds__(256) void frag_a(
    const float* __restrict__ src, u16* __restrict__ dh, u16* __restrict__ dl)
{
  __shared__ float T[128][68];
  const int kt = blockIdx.x;
  const int mb = blockIdx.y;
  const int tid = threadIdx.x;
#pragma unroll
  for (int rep = 0; rep < 8; ++rep) {
    int idx = tid + rep * 256;
    int row = idx >> 4, c4 = (idx & 15) * 4;
    float4 v = *reinterpret_cast<const float4*>(&src[(size_t)(mb*128 + row) * 4096 + kt*64 + c4]);
    *reinterpret_cast<float4*>(&T[row][c4]) = v;
  }
  __syncthreads();
#pragma unroll
  for (int rep = 0; rep < 4; ++rep) {
    int c = tid + rep * 256;
    int mt = c >> 7, rem = c & 127, kk = rem >> 6, l = rem & 63;
    const int rr = mt*16 + (l & 15), c0 = kk*32 + (l >> 4)*8;
    unsigned hh4[4], ll4[4];
#pragma unroll
    for (int p = 0; p < 4; ++p)
      cvt_hi_lo(T[rr][c0 + 2*p], T[rr][c0 + 2*p + 1], hh4[p], ll4[p]);
    size_t off = (((size_t)(kt*128 + mb*8 + mt)) * 2 + kk) * 512 + (size_t)l * 8;
    *reinterpret_cast<uint4*>(&dh[off]) = make_uint4(hh4[0],hh4[1],hh4[2],hh4[3]);
    *reinterpret_cast<uint4*>(&dl[off]) = make_uint4(ll4[0],ll4[1],ll4[2],ll4[3]);
  }
}

// ===========================================================================
// gemm128_core<NF,RQ> (round-13 verified): hoisted staging, 3 hi/lo passes.
// ===========================================================================
template<int NF, bool RQ>
__device__ __forceinline__ void gemm128_core(
    const u16* __restrict__ PAh, const u16* __restrict__ PAl,
    const u16* __restrict__ PBh, const u16* __restrict__ PBl,
    float* __restrict__ C0, float* __restrict__ C1, float* __restrict__ C2,
    int ldc0, int Nt16, int mb, int nb, u16* L)
{
  const int tid  = threadIdx.x;
  const int lane = tid & 63;
  const int wid  = tid >> 6;
  const int loff = lane * 8;
  const int wm4  = (wid >> 2) * 4;
  const int wnf  = (wid & 3) * NF;
  constexpr int BNT  = 4 * NF;
  constexpr int NCHW = 2 + NF;

  u16* A0 = L;
  u16* A1 = L + 8192;
  u16* B0 = L + 16384;
  u16* B1 = L + 16384 + BNT*1024;

  f32x4 acc[4][NF];
#pragma unroll
  for (int i = 0; i < 4; ++i)
#pragma unroll
    for (int j = 0; j < NF; ++j) acc[i][j] = (f32x4){0.f,0.f,0.f,0.f};

  const u16* sp[NCHW];
  int   dlo[NCHW];
  int   dadd[NCHW];
  size_t adv2[NCHW];
  const size_t aSlab = 131072;
  const size_t bSlab = (size_t)Nt16 * 1024;
#pragma unroll
  for (int i = 0; i < NCHW; ++i) {
    int c = wid + 8*i;
    if (c < 8) {
      sp[i]  = PAh + (size_t)(mb*8 + c)*1024 + loff;
      dlo[i] = c*512;             dadd[i] = 8192;      adv2[i] = aSlab - 512;
    } else if (c < 16) {
      int m = c - 8;
      sp[i]  = PAl + (size_t)(mb*8 + m)*1024 + loff;
      dlo[i] = 4096 + m*512;      dadd[i] = 8192;      adv2[i] = aSlab - 512;
    } else if (c < 16 + BNT) {
      int n = c - 16;
      sp[i]  = PBh + (size_t)(nb*BNT + n)*1024 + loff;
      dlo[i] = 16384 + n*512;     dadd[i] = BNT*1024;  adv2[i] = bSlab - 512;
    } else {
      int n = c - 16 - BNT;
      sp[i]  = PBl + (size_t)(nb*BNT + n)*1024 + loff;
      dlo[i] = 16384 + BNT*512 + n*512; dadd[i] = BNT*1024; adv2[i] = bSlab - 512;
    }
  }

#pragma unroll
  for (int i = 0; i < NCHW; ++i) {
    gload_lds16(sp[i], L + dlo[i]);
    sp[i] += 512;
  }
  __syncthreads();

  for (int t = 0; t < 128; ++t) {
    u16* la = (t & 1) ? A1 : A0;
    u16* lb = (t & 1) ? B1 : B0;
    if (t < 127) {
      const int p = (t + 1) & 1;
#pragma unroll
      for (int i = 0; i < NCHW; ++i) {
        gload_lds16(sp[i], L + dlo[i] + (p ? dadd[i] : 0));
        sp[i] += p ? adv2[i] : 512;
      }
    }

    s16x8 ah[4], al[4], bh[NF], bl[NF];
#pragma unroll
    for (int mf = 0; mf < 4; ++mf)
      ah[mf] = *reinterpret_cast<const s16x8*>(&la[(wm4+mf)*512 + loff]);
#pragma unroll
    for (int nf = 0; nf < NF; ++nf)
      bh[nf] = *reinterpret_cast<const s16x8*>(&lb[(wnf+nf)*512 + loff]);
    __builtin_amdgcn_s_setprio(1);
#pragma unroll
    for (int nf = 0; nf < NF; ++nf)
#pragma unroll
      for (int mf = 0; mf < 4; ++mf)
        acc[mf][nf] = MFMA(ah[mf], bh[nf], acc[mf][nf]);
    __builtin_amdgcn_s_setprio(0);
#pragma unroll
    for (int mf = 0; mf < 4; ++mf)
      al[mf] = *reinterpret_cast<const s16x8*>(&la[4096 + (wm4+mf)*512 + loff]);
    __builtin_amdgcn_s_setprio(1);
#pragma unroll
    for (int nf = 0; nf < NF; ++nf)
#pragma unroll
      for (int mf = 0; mf < 4; ++mf)
        acc[mf][nf] = MFMA(al[mf], bh[nf], acc[mf][nf]);
    __builtin_amdgcn_s_setprio(0);
#pragma unroll
    for (int nf = 0; nf < NF; ++nf)
      bl[nf] = *reinterpret_cast<const s16x8*>(&lb[BNT*512 + (wnf+nf)*512 + loff]);
    __builtin_amdgcn_s_setprio(1);
#pragma unroll
    for (int nf = 0; nf < NF; ++nf)
#pragma unroll
      for (int mf = 0; mf < 4; ++mf)
        acc[mf][nf] = MFMA(ah[mf], bl[nf], acc[mf][nf]);
    __builtin_amdgcn_s_setprio(0);
    __syncthreads();
  }

  const int lg = lane >> 4, lr = lane & 15;
  const int rowb = mb*128 + (wid >> 2) * 64;
#pragma unroll
  for (int mf = 0; mf < 4; ++mf)
#pragma unroll
    for (int nf = 0; nf < NF; ++nf)
#pragma unroll
      for (int r = 0; r < 4; ++r) {
        int row = rowb + mf*16 + lg*4 + r;
        float v = acc[mf][nf][r];
        int gcol = nb*(NF*64) + (wid & 3)*(NF*16) + nf*16 + lr;
        if constexpr (RQ) {
          if (gcol < 4096)      C0[(size_t)row * 4096 + gcol] = v;
          else if (gcol < 5120) C1[(size_t)row * 1024 + (gcol - 4096)] = v;
          else                  C2[(size_t)row * 1024 + (gcol - 5120)] = v;
        } else {
          C0[(size_t)row * ldc0 + gcol] = v;
        }
      }
}

__global__ __launch_bounds__(512, 4) void gemm_qkv3(
    const u16* __restrict__ XAh, const u16* __restrict__ XAl,
    const u16* __restrict__ WBh, const u16* __restrict__ WBl,
    float* __restrict__ qb, float* __restrict__ kb, float* __restrict__ vb)
{
  __shared__ __attribute__((aligned(16))) u16 L[40960];
  int id = blockIdx.x;
  int xcd = id & 7, c = id >> 3;
  int nb = xcd * 4 + (c >> 4);
  int mb = c & 15;
  gemm128_core<3, true>(XAh, XAl, WBh, WBl, qb, kb, vb, 0, 384, mb, nb, L);
}

__global__ __launch_bounds__(512, 4) void gemm_out3(
    const u16* __restrict__ ABh, const u16* __restrict__ ABl,
    const u16* __restrict__ WOh, const u16* __restrict__ WOl,
    float* __restrict__ outp)
{
  __shared__ __attribute__((aligned(16))) u16 L[32768];
  int id = blockIdx.x;
  int xcd = id & 7, c = id >> 3;
  int nb = xcd * 4 + (c >> 4);
  int mb = c & 15;
  gemm128_core<2, false>(ABh, ABl, WOh, WOl, outp, nullptr, nullptr,
                         4096, 256, mb, nb, L);
}

// ===========================================================================
// frag_kv: post-GEMM K,V -> fragment planes, K-RoPE fused (pack-converted).
// ===========================================================================
__global__ __launch_bounds__(256) void frag_kv(
    const float* __restrict__ kb, const float* __restrict__ vb,
    const float* __restrict__ cosT, const float* __restrict__ sinT,
    u16* __restrict__ KFh, u16* __restrict__ KFl,
    u16* __restrict__ VFh, u16* __restrict__ VFl)
{
  __shared__ float T[32][132];
  const int bid  = blockIdx.x;
  const int isV  = bid >> 9;
  const int bkvh = (bid >> 5) & 15;
  const int chnk = bid & 31;
  const int tid  = threadIdx.x;
  const int b    = bkvh >> 3, kvh = bkvh & 7;

  const float* src = isV ? vb : kb;
  {
    int r0 = tid >> 5, c4 = (tid & 31) * 4;
    float sgn = (c4 < 64) ? -1.f : 1.f;
#pragma unroll
    for (int it = 0; it < 4; ++it) {
      int row = r0 + it * 8;
      int srow = chnk*32 + row;
      const float* rp = &src[(((size_t)(b * S_ + srow)) * HKV_ + kvh) * HD_];
      float4 v = *reinterpret_cast<const float4*>(rp + c4);
      if (!isV) {
        float4 p  = *reinterpret_cast<const float4*>(rp + (c4 ^ 64));
        float4 cc = *reinterpret_cast<const float4*>(&cosT[((size_t)(b*S_ + srow))*HD_ + c4]);
        float4 ss = *reinterpret_cast<const float4*>(&sinT[((size_t)(b*S_ + srow))*HD_ + c4]);
        v.x = v.x*cc.x + sgn*p.x*ss.x;
        v.y = v.y*cc.y + sgn*p.y*ss.y;
        v.z = v.z*cc.z + sgn*p.z*ss.z;
        v.w = v.w*cc.w + sgn*p.w*ss.w;
      }
      *reinterpret_cast<float4*>(&T[row][c4]) = v;
    }
  }
  __syncthreads();
#pragma unroll
  for (int rep = 0; rep < 2; ++rep) {
    int c2 = tid + rep * 256;
    int l = c2 & 63;
    unsigned hh4[4], ll4[4];
    if (!isV) {
      int f = c2 >> 6, st_loc = f >> 2, dt = f & 3;
      const int rr = st_loc*16 + (l & 15), c0 = dt*32 + (l >> 4)*8;
#pragma unroll
      for (int p = 0; p < 4; ++p)
        cvt_hi_lo(T[rr][c0 + 2*p], T[rr][c0 + 2*p + 1], hh4[p], ll4[p]);
      size_t off = ((size_t)bkvh*64 + chnk*2) * 2048 + (size_t)c2 * 8;
      *reinterpret_cast<uint4*>(&KFh[off]) = make_uint4(hh4[0],hh4[1],hh4[2],hh4[3]);
      *reinterpret_cast<uint4*>(&KFl[off]) = make_uint4(ll4[0],ll4[1],ll4[2],ll4[3]);
    } else {
      int dt16 = c2 >> 6;
      const int r0 = (l >> 4)*8, cc = dt16*16 + (l & 15);
#pragma unroll
      for (int p = 0; p < 4; ++p)
        cvt_hi_lo(T[r0 + 2*p][cc], T[r0 + 2*p + 1][cc], hh4[p], ll4[p]);
      size_t off = ((size_t)bkvh*32 + chnk) * 4096 + (size_t)c2 * 8;
      *reinterpret_cast<uint4*>(&VFh[off]) = make_uint4(hh4[0],hh4[1],hh4[2],hh4[3]);
      *reinterpret_cast<uint4*>(&VFl[off]) = make_uint4(ll4[0],ll4[1],ll4[2],ll4[3]);
    }
  }
}

// ===========================================================================
// attn3 (round-13 verified): fragment-staged flash attention, Q-RoPE fused.
// KVBLK=64, 8 waves. Larger KV tiles amortize softmax/barrier overhead
// (round-14 lesson: KVBLK=32 doubled per-tile costs, net regression).
// ===========================================================================
__global__ __launch_bounds__(512) void attn3(
    const float* __restrict__ qb,
    const float* __restrict__ cosT, const float* __restrict__ sinT,
    const u16* __restrict__ KFh, const u16* __restrict__ KFl,
    const u16* __restrict__ VFh, const u16* __restrict__ VFl,
    float* __restrict__ ob)
{
  __shared__ __attribute__((aligned(16))) u16 Klds[16384];
  __shared__ __attribute__((aligned(16))) u16 Vlds[16384];
  __shared__ u16 Ph[8][16][68], Pl[8][16][68];

  const int tid  = threadIdx.x;
  const int lane = tid & 63;
  const int wid  = tid >> 6;
  const int lr   = lane & 15;
  const int lg   = lane >> 4;
  const int loff = lane * 8;
  const int qt   = blockIdx.x;
  const int bh   = blockIdx.y;
  const int b    = bh >> 5, h = bh & 31;
  const int bkvh = b * 8 + (h >> 2);

  s16x8 qh[4], ql[4];
  {
    const int qrow = qt * 128 + wid * 16 + lr;
    const float* qp = qb + ((size_t)((b * S_ + qrow) * HQ_ + h)) * HD_;
    const float* cp = cosT + ((size_t)(b * S_ + qrow)) * HD_;
    const float* sp = sinT + ((size_t)(b * S_ + qrow)) * HD_;
#pragma unroll
    for (int kc = 0; kc < 4; ++kc) {
      const int d0 = kc * 32 + lg * 8;
      const float sgn = (d0 < 64) ? -1.f : 1.f;
      float4 v0 = *reinterpret_cast<const float4*>(qp + d0);
      float4 v1 = *reinterpret_cast<const float4*>(qp + d0 + 4);
      float4 p0 = *reinterpret_cast<const float4*>(qp + (d0 ^ 64));
      float4 p1 = *reinterpret_cast<const float4*>(qp + (d0 ^ 64) + 4);
      float4 c0 = *reinterpret_cast<const float4*>(cp + d0);
      float4 c1 = *reinterpret_cast<const float4*>(cp + d0 + 4);
      float4 s0 = *reinterpret_cast<const float4*>(sp + d0);
      float4 s1 = *reinterpret_cast<const float4*>(sp + d0 + 4);
      float4 r0, r1;
      r0.x = v0.x*c0.x + sgn*p0.x*s0.x;  r0.y = v0.y*c0.y + sgn*p0.y*s0.y;
      r0.z = v0.z*c0.z + sgn*p0.z*s0.z;  r0.w = v0.w*c0.w + sgn*p0.w*s0.w;
      r1.x = v1.x*c1.x + sgn*p1.x*s1.x;  r1.y = v1.y*c1.y + sgn*p1.y*s1.y;
      r1.z = v1.z*c1.z + sgn*p1.z*s1.z;  r1.w = v1.w*c1.w + sgn*p1.w*s1.w;
      uint4 h4, l4; pack8(r0, r1, h4, l4);
      qh[kc] = *reinterpret_cast<s16x8*>(&h4);
      ql[kc] = *reinterpret_cast<s16x8*>(&l4);
    }
  }

  f32x4 acc_o[8];
#pragma unroll
  for (int df = 0; df < 8; ++df) acc_o[df] = (f32x4){0.f, 0.f, 0.f, 0.f};
  float m_run[4] = {-1e30f, -1e30f, -1e30f, -1e30f};
  float l_run[4] = {0.f, 0.f, 0.f, 0.f};

  const u16* gKh = KFh + (size_t)bkvh * 131072;
  const u16* gKl = KFl + (size_t)bkvh * 131072;
  const u16* gVh = VFh + (size_t)bkvh * 131072;
  const u16* gVl = VFl + (size_t)bkvh * 131072;

#pragma unroll
  for (int i = 0; i < 4; ++i) {
    int idx = wid * 4 + i;
    const u16* src = (idx < 16) ? (gKh + idx*512) : (gKl + (idx-16)*512);
    u16* dst = Klds + ((idx < 16) ? idx*512 : 8192 + (idx-16)*512);
    gload_lds16(src + loff, dst);
  }
  __syncthreads();

  for (int t = 0; t < 16; ++t) {
#pragma unroll
    for (int i = 0; i < 4; ++i) {
      int idx = wid * 4 + i;
      const u16* src = (idx < 16) ? (gVh + t*8192 + idx*512)
                                  : (gVl + t*8192 + (idx-16)*512);
      u16* dst = Vlds + ((idx < 16) ? idx*512 : 8192 + (idx-16)*512);
      gload_lds16(src + loff, dst);
    }

    f32x4 accs[4];
#pragma unroll
    for (int nf = 0; nf < 4; ++nf) {
      accs[nf] = (f32x4){0.f, 0.f, 0.f, 0.f};
      s16x8 kh8[4], kl8[4];
#pragma unroll
      for (int kc = 0; kc < 4; ++kc) {
        kh8[kc] = *reinterpret_cast<const s16x8*>(&Klds[nf*2048 + kc*512 + loff]);
        kl8[kc] = *reinterpret_cast<const s16x8*>(&Klds[8192 + nf*2048 + kc*512 + loff]);
      }
#pragma unroll
      for (int kc = 0; kc < 4; ++kc) {
        accs[nf] = MFMA(qh[kc], kh8[kc], accs[nf]);
        accs[nf] = MFMA(ql[kc], kh8[kc], accs[nf]);
        accs[nf] = MFMA(qh[kc], kl8[kc], accs[nf]);
      }
    }
#pragma unroll
    for (int nf = 0; nf < 4; ++nf) accs[nf] *= SCALE_;

    float corr[4], rsum[4];
#pragma unroll
    for (int r = 0; r < 4; ++r) {
      float t0 = fmaxf(fmaxf(accs[0][r], accs[1][r]), fmaxf(accs[2][r], accs[3][r]));
      t0 = fmaxf(t0, __shfl_xor(t0, 1));
      t0 = fmaxf(t0, __shfl_xor(t0, 2));
      t0 = fmaxf(t0, __shfl_xor(t0, 4));
      t0 = fmaxf(t0, __shfl_xor(t0, 8));
      float mnew = fmaxf(m_run[r], t0);
      corr[r] = __expf(m_run[r] - mnew);
      m_run[r] = mnew;
      rsum[r] = 0.f;
    }
#pragma unroll
    for (int nf = 0; nf < 4; ++nf)
#pragma unroll
      for (int r = 0; r < 4; ++r) {
        float p = __expf(accs[nf][r] - m_run[r]);
        rsum[r] += p;
        u16 ph, pl;
        split2(p, ph, pl);
        Ph[wid][lg*4 + r][nf*16 + lr] = ph;
        Pl[wid][lg*4 + r][nf*16 + lr] = pl;
      }
#pragma unroll
    for (int r = 0; r < 4; ++r) {
      float s = rsum[r];
      s += __shfl_xor(s, 1); s += __shfl_xor(s, 2);
      s += __shfl_xor(s, 4); s += __shfl_xor(s, 8);
      l_run[r] = l_run[r] * corr[r] + s;
    }
#pragma unroll
    for (int df = 0; df < 8; ++df)
#pragma unroll
      for (int r = 0; r < 4; ++r) acc_o[df][r] *= corr[r];

    __syncthreads();

    if (t < 15) {
#pragma unroll
      for (int i = 0; i < 4; ++i) {
        int idx = wid * 4 + i;
        const u16* src = (idx < 16) ? (gKh + (t+1)*8192 + idx*512)
                                    : (gKl + (t+1)*8192 + (idx-16)*512);
        u16* dst = Klds + ((idx < 16) ? idx*512 : 8192 + (idx-16)*512);
        gload_lds16(src + loff, dst);
      }
    }

    s16x8 pa_h[2], pa_l[2];
#pragma unroll
    for (int kc = 0; kc < 2; ++kc) {
      pa_h[kc] = *reinterpret_cast<const s16x8*>(&Ph[wid][lr][kc*32 + lg*8]);
      pa_l[kc] = *reinterpret_cast<const s16x8*>(&Pl[wid][lr][kc*32 + lg*8]);
    }
#pragma unroll
    for (int df = 0; df < 8; ++df) {
      s16x8 vh8[2], vl8[2];
#pragma unroll
      for (int kc = 0; kc < 2; ++kc) {
        vh8[kc] = *reinterpret_cast<const s16x8*>(&Vlds[kc*4096 + df*512 + loff]);
        vl8[kc] = *reinterpret_cast<const s16x8*>(&Vlds[8192 + kc*4096 + df*512 + loff]);
      }
#pragma unroll
      for (int kc = 0; kc < 2; ++kc) {
        acc_o[df] = MFMA(pa_h[kc], vh8[kc], acc_o[df]);
        acc_o[df] = MFMA(pa_l[kc], vh8[kc], acc_o[df]);
        acc_o[df] = MFMA(pa_h[kc], vl8[kc], acc_o[df]);
      }
    }
    __syncthreads();
  }

  float inv_l[4];
#pragma unroll
  for (int r = 0; r < 4; ++r) inv_l[r] = 1.f / l_run[r];
#pragma unroll
  for (int df = 0; df < 8; ++df)
#pragma unroll
    for (int r = 0; r < 4; ++r) {
      int row = qt * 128 + wid * 16 + lg * 4 + r;
      ob[((size_t)((b * S_ + row) * HQ_ + h)) * HD_ + df*16 + lr] = acc_o[df][r] * inv_l[r];
    }
}

// ---------------------------------------------------------------------------
extern "C" void kernel_launch(void* const* d_in, const int* in_sizes, int n_in,
                              void* d_out, int out_size, void* d_ws, size_t ws_size,
                              hipStream_t stream)
{
  const float* hs   = (const float*)d_in[0];
  const float* cosT = (const float*)d_in[1];
  const float* sinT = (const float*)d_in[2];
  const float* Wq   = (const float*)d_in[3];
  const float* Wk   = (const float*)d_in[4];
  const float* Wv   = (const float*)d_in[5];
  const float* Wo   = (const float*)d_in[6];
  float* out = (float*)d_out;

  float* qb = (float*)d_ws;                 // 8388608 f32
  float* kb = qb + 8388608;                 // 2097152
  float* vb = kb + 2097152;                 // 2097152
  float* ab = vb + 2097152;                 // 8388608
  u16*   FR = (u16*)(ab + 8388608);

  // Round-13 verified pipeline (WS212 known present; same layout fits WS208+)
  u16* XAh = FR;
  u16* XAl = FR + 8388608;
  u16* WBh = FR + 16777216;
  u16* WBl = FR + 41943040;
  u16* KFh = FR + 16777216;
  u16* KFl = FR + 18874368;
  u16* VFh = FR + 20971520;
  u16* VFl = FR + 23068672;
  u16* WOh = FR + 25165824;
  u16* WOl = FR + 41943040;

  frag_a<<<dim3(64,16), 256, 0, stream>>>(hs, XAh, XAl);
  frag_b2<<<dim3(128,64), 256, 0, stream>>>(Wq, WBh, WBl, 4096, 0, 384, 0);
  frag_b2<<<dim3(128,16), 256, 0, stream>>>(Wk, WBh, WBl, 1024, 0, 384, 256);
  frag_b2<<<dim3(128,16), 256, 0, stream>>>(Wv, WBh, WBl, 1024, 0, 384, 320);
  gemm_qkv3<<<512, 512, 0, stream>>>(XAh, XAl, WBh, WBl, qb, kb, vb);
  frag_kv<<<1024, 256, 0, stream>>>(kb, vb, cosT, sinT, KFh, KFl, VFh, VFl);
  frag_b2<<<dim3(128,64), 256, 0, stream>>>(Wo, WOh, WOl, 4096, 0, 256, 0);
  attn3<<<dim3(8, 64), 512, 0, stream>>>(qb, cosT, sinT, KFh, KFl, VFh, VFl, ab);
  frag_a<<<dim3(64,16), 256, 0, stream>>>(ab, XAh, XAl);
  gemm_out3<<<512, 512, 0, stream>>>(XAh, XAl, WOh, WOl, out);
}

// Round 16
// 646.435 us; speedup vs baseline: 1.0507x; 1.0019x over previous
//
#include <hip/hip_runtime.h>

#define B_   2
#define S_   1024
#define D_   4096
#define HQ_  32
#define HKV_ 8
#define HD_  128
#define SCALE_ 0.08838834764831845f

typedef unsigned short u16;
typedef __attribute__((ext_vector_type(8))) short s16x8;
typedef __attribute__((ext_vector_type(4))) short s16x4;
typedef __attribute__((ext_vector_type(4))) float f32x4;

#define MFMA(a,b,c) __builtin_amdgcn_mfma_f32_16x16x32_bf16((a),(b),(c),0,0,0)

__device__ __forceinline__ u16 bf16_rne(float x) {
  unsigned u = __float_as_uint(x);
  u += 0x7fffu + ((u >> 16) & 1u);
  return (u16)(u >> 16);
}
__device__ __forceinline__ float bf16_up(u16 h) {
  return __uint_as_float(((unsigned)h) << 16);
}
__device__ __forceinline__ void split2(float x, u16& h, u16& l) {
  h = bf16_rne(x);
  l = bf16_rne(x - bf16_up(h));
}

// packed hi/lo split (RNE, identical to split2; validated rounds 3-15)
__device__ __forceinline__ void cvt_hi_lo(float a, float b, unsigned& hi, unsigned& lo) {
  unsigned h, l;
  asm("v_cvt_pk_bf16_f32 %0, %1, %2" : "=v"(h) : "v"(a), "v"(b));
  float ra = __uint_as_float(h << 16);
  float rb = __uint_as_float(h & 0xffff0000u);
  float la = a - ra, lb = b - rb;
  asm("v_cvt_pk_bf16_f32 %0, %1, %2" : "=v"(l) : "v"(la), "v"(lb));
  hi = h; lo = l;
}
__device__ __forceinline__ void pack8(float4 x, float4 y, uint4& h, uint4& l) {
  unsigned h0,h1,h2,h3,l0,l1,l2,l3;
  cvt_hi_lo(x.x, x.y, h0, l0);
  cvt_hi_lo(x.z, x.w, h1, l1);
  cvt_hi_lo(y.x, y.y, h2, l2);
  cvt_hi_lo(y.z, y.w, h3, l3);
  h = make_uint4(h0,h1,h2,h3); l = make_uint4(l0,l1,l2,l3);
}

typedef const __attribute__((address_space(1))) void* gas_ptr;
typedef __attribute__((address_space(3))) void* las_ptr;
__device__ __forceinline__ void gload_lds16(const void* g, void* l) {
  __builtin_amdgcn_global_load_lds((gas_ptr)g, (las_ptr)l, 16, 0, 0);
}

// ===========================================================================
// frag bodies (device fns; logic identical to round-15 kernels, LDS passed in)
// ===========================================================================
__device__ __forceinline__ void frag_b2_body(
    const float* __restrict__ W, u16* __restrict__ dh, u16* __restrict__ dl,
    int N, int n0, int Ntot16, int ntoff, int kt, int nbk, float* T /*32x68*/)
{
  const int tid = threadIdx.x;
#pragma unroll
  for (int rep = 0; rep < 2; ++rep) {
    int idx = tid + rep * 256;
    int row = idx >> 4, c4 = (idx & 15) * 4;
    float4 v = *reinterpret_cast<const float4*>(&W[(size_t)(kt*32 + row) * N + n0 + nbk*64 + c4]);
    *reinterpret_cast<float4*>(&T[row*68 + c4]) = v;
  }
  __syncthreads();
  int c = tid;
  int nt = c >> 6, l = c & 63;
  const size_t base = (((size_t)(kt >> 1) * Ntot16 + ntoff + nbk*4 + nt) * 2 + (kt & 1)) * 512;
  const int r0 = (l >> 4) * 8, cc = nt*16 + (l & 15);
  unsigned hh4[4], ll4[4];
#pragma unroll
  for (int p = 0; p < 4; ++p)
    cvt_hi_lo(T[(r0 + 2*p)*68 + cc], T[(r0 + 2*p + 1)*68 + cc], hh4[p], ll4[p]);
  *reinterpret_cast<uint4*>(&dh[base + (size_t)l * 8]) = make_uint4(hh4[0],hh4[1],hh4[2],hh4[3]);
  *reinterpret_cast<uint4*>(&dl[base + (size_t)l * 8]) = make_uint4(ll4[0],ll4[1],ll4[2],ll4[3]);
}

__device__ __forceinline__ void frag_a_body(
    const float* __restrict__ src, u16* __restrict__ dh, u16* __restrict__ dl,
    int kt, int mb, float* T /*128x68*/)
{
  const int tid = threadIdx.x;
#pragma unroll
  for (int rep = 0; rep < 8; ++rep) {
    int idx = tid + rep * 256;
    int row = idx >> 4, c4 = (idx & 15) * 4;
    float4 v = *reinterpret_cast<const float4*>(&src[(size_t)(mb*128 + row) * 4096 + kt*64 + c4]);
    *reinterpret_cast<float4*>(&T[row*68 + c4]) = v;
  }
  __syncthreads();
#pragma unroll
  for (int rep = 0; rep < 4; ++rep) {
    int c = tid + rep * 256;
    int mt = c >> 7, rem = c & 127, kk = rem >> 6, l = rem & 63;
    const int rr = mt*16 + (l & 15), c0 = kk*32 + (l >> 4)*8;
    unsigned hh4[4], ll4[4];
#pragma unroll
    for (int p = 0; p < 4; ++p)
      cvt_hi_lo(T[rr*68 + c0 + 2*p], T[rr*68 + c0 + 2*p + 1], hh4[p], ll4[p]);
    size_t off = (((size_t)(kt*128 + mb*8 + mt)) * 2 + kk) * 512 + (size_t)l * 8;
    *reinterpret_cast<uint4*>(&dh[off]) = make_uint4(hh4[0],hh4[1],hh4[2],hh4[3]);
    *reinterpret_cast<uint4*>(&dl[off]) = make_uint4(ll4[0],ll4[1],ll4[2],ll4[3]);
  }
}

__device__ __forceinline__ void frag_kv_body(
    const float* __restrict__ kb, const float* __restrict__ vb,
    const float* __restrict__ cosT, const float* __restrict__ sinT,
    u16* __restrict__ KFh, u16* __restrict__ KFl,
    u16* __restrict__ VFh, u16* __restrict__ VFl,
    int bid, float* T /*32x132*/)
{
  const int isV  = bid >> 9;
  const int bkvh = (bid >> 5) & 15;
  const int chnk = bid & 31;
  const int tid  = threadIdx.x;
  const int b    = bkvh >> 3, kvh = bkvh & 7;

  const float* src = isV ? vb : kb;
  {
    int r0 = tid >> 5, c4 = (tid & 31) * 4;
    float sgn = (c4 < 64) ? -1.f : 1.f;
#pragma unroll
    for (int it = 0; it < 4; ++it) {
      int row = r0 + it * 8;
      int srow = chnk*32 + row;
      const float* rp = &src[(((size_t)(b * S_ + srow)) * HKV_ + kvh) * HD_];
      float4 v = *reinterpret_cast<const float4*>(rp + c4);
      if (!isV) {
        float4 p  = *reinterpret_cast<const float4*>(rp + (c4 ^ 64));
        float4 cc = *reinterpret_cast<const float4*>(&cosT[((size_t)(b*S_ + srow))*HD_ + c4]);
        float4 ss = *reinterpret_cast<const float4*>(&sinT[((size_t)(b*S_ + srow))*HD_ + c4]);
        v.x = v.x*cc.x + sgn*p.x*ss.x;
        v.y = v.y*cc.y + sgn*p.y*ss.y;
        v.z = v.z*cc.z + sgn*p.z*ss.z;
        v.w = v.w*cc.w + sgn*p.w*ss.w;
      }
      *reinterpret_cast<float4*>(&T[row*132 + c4]) = v;
    }
  }
  __syncthreads();
#pragma unroll
  for (int rep = 0; rep < 2; ++rep) {
    int c2 = tid + rep * 256;
    int l = c2 & 63;
    unsigned hh4[4], ll4[4];
    if (!isV) {
      int f = c2 >> 6, st_loc = f >> 2, dt = f & 3;
      const int rr = st_loc*16 + (l & 15), c0 = dt*32 + (l >> 4)*8;
#pragma unroll
      for (int p = 0; p < 4; ++p)
        cvt_hi_lo(T[rr*132 + c0 + 2*p], T[rr*132 + c0 + 2*p + 1], hh4[p], ll4[p]);
      size_t off = ((size_t)bkvh*64 + chnk*2) * 2048 + (size_t)c2 * 8;
      *reinterpret_cast<uint4*>(&KFh[off]) = make_uint4(hh4[0],hh4[1],hh4[2],hh4[3]);
      *reinterpret_cast<uint4*>(&KFl[off]) = make_uint4(ll4[0],ll4[1],ll4[2],ll4[3]);
    } else {
      int dt16 = c2 >> 6;
      const int r0 = (l >> 4)*8, cc = dt16*16 + (l & 15);
#pragma unroll
      for (int p = 0; p < 4; ++p)
        cvt_hi_lo(T[(r0 + 2*p)*132 + cc], T[(r0 + 2*p + 1)*132 + cc], hh4[p], ll4[p]);
      size_t off = ((size_t)bkvh*32 + chnk) * 4096 + (size_t)c2 * 8;
      *reinterpret_cast<uint4*>(&VFh[off]) = make_uint4(hh4[0],hh4[1],hh4[2],hh4[3]);
      *reinterpret_cast<uint4*>(&VFl[off]) = make_uint4(ll4[0],ll4[1],ll4[2],ll4[3]);
    }
  }
}

// ===========================================================================
// mega_frag1: frag_a(hs) + frag_b2(Wq) + frag_b2(Wk) + frag_b2(Wv)
// (all independent; disjoint outputs). grid 13312 x 256.
// ===========================================================================
__global__ __launch_bounds__(256) void mega_frag1(
    const float* __restrict__ hs,
    const float* __restrict__ Wq, const float* __restrict__ Wk,
    const float* __restrict__ Wv,
    u16* __restrict__ XAh, u16* __restrict__ XAl,
    u16* __restrict__ WBh, u16* __restrict__ WBl)
{
  __shared__ float T[8704];   // 128x68
  int bid = blockIdx.x;
  if (bid < 1024) {
    frag_a_body(hs, XAh, XAl, bid & 63, bid >> 6, T);
  } else if (bid < 9216) {
    int v = bid - 1024;
    frag_b2_body(Wq, WBh, WBl, 4096, 0, 384, 0,   v & 127, v >> 7, T);
  } else if (bid < 11264) {
    int v = bid - 9216;
    frag_b2_body(Wk, WBh, WBl, 1024, 0, 384, 256, v & 127, v >> 7, T);
  } else {
    int v = bid - 11264;
    frag_b2_body(Wv, WBh, WBl, 1024, 0, 384, 320, v & 127, v >> 7, T);
  }
}

// ===========================================================================
// mega_frag2: frag_kv + frag_b2(Wo) (both depend only on gemm_qkv3; disjoint
// outputs). grid 9216 x 256.
// ===========================================================================
__global__ __launch_bounds__(256) void mega_frag2(
    const float* __restrict__ kb, const float* __restrict__ vb,
    const float* __restrict__ cosT, const float* __restrict__ sinT,
    u16* __restrict__ KFh, u16* __restrict__ KFl,
    u16* __restrict__ VFh, u16* __restrict__ VFl,
    const float* __restrict__ Wo,
    u16* __restrict__ WOh, u16* __restrict__ WOl)
{
  __shared__ float T[4224];   // 32x132
  int bid = blockIdx.x;
  if (bid < 1024) {
    frag_kv_body(kb, vb, cosT, sinT, KFh, KFl, VFh, VFl, bid, T);
  } else {
    int v = bid - 1024;
    frag_b2_body(Wo, WOh, WOl, 4096, 0, 256, 0, v & 127, v >> 7, T);
  }
}

// standalone frag_a (for ab -> fragment planes before OUT gemm)
__global__ __launch_bounds__(256) void frag_a_k(
    const float* __restrict__ src, u16* __restrict__ dh, u16* __restrict__ dl)
{
  __shared__ float T[8704];
  frag_a_body(src, dh, dl, blockIdx.x, blockIdx.y, T);
}

// ===========================================================================
// gemm128_core<NF,RQ> (round-13 verified): hoisted staging, 3 hi/lo passes.
// ===========================================================================
template<int NF, bool RQ>
__device__ __forceinline__ void gemm128_core(
    const u16* __restrict__ PAh, const u16* __restrict__ PAl,
    const u16* __restrict__ PBh, const u16* __restrict__ PBl,
    float* __restrict__ C0, float* __restrict__ C1, float* __restrict__ C2,
    int ldc0, int Nt16, int mb, int nb, u16* L)
{
  const int tid  = threadIdx.x;
  const int lane = tid & 63;
  const int wid  = tid >> 6;
  const int loff = lane * 8;
  const int wm4  = (wid >> 2) * 4;
  const int wnf  = (wid & 3) * NF;
  constexpr int BNT  = 4 * NF;
  constexpr int NCHW = 2 + NF;

  u16* A0 = L;
  u16* A1 = L + 8192;
  u16* B0 = L + 16384;
  u16* B1 = L + 16384 + BNT*1024;

  f32x4 acc[4][NF];
#pragma unroll
  for (int i = 0; i < 4; ++i)
#pragma unroll
    for (int j = 0; j < NF; ++j) acc[i][j] = (f32x4){0.f,0.f,0.f,0.f};

  const u16* sp[NCHW];
  int   dlo[NCHW];
  int   dadd[NCHW];
  size_t adv2[NCHW];
  const size_t aSlab = 131072;
  const size_t bSlab = (size_t)Nt16 * 1024;
#pragma unroll
  for (int i = 0; i < NCHW; ++i) {
    int c = wid + 8*i;
    if (c < 8) {
      sp[i]  = PAh + (size_t)(mb*8 + c)*1024 + loff;
      dlo[i] = c*512;             dadd[i] = 8192;      adv2[i] = aSlab - 512;
    } else if (c < 16) {
      int m = c - 8;
      sp[i]  = PAl + (size_t)(mb*8 + m)*1024 + loff;
      dlo[i] = 4096 + m*512;      dadd[i] = 8192;      adv2[i] = aSlab - 512;
    } else if (c < 16 + BNT) {
      int n = c - 16;
      sp[i]  = PBh + (size_t)(nb*BNT + n)*1024 + loff;
      dlo[i] = 16384 + n*512;     dadd[i] = BNT*1024;  adv2[i] = bSlab - 512;
    } else {
      int n = c - 16 - BNT;
      sp[i]  = PBl + (size_t)(nb*BNT + n)*1024 + loff;
      dlo[i] = 16384 + BNT*512 + n*512; dadd[i] = BNT*1024; adv2[i] = bSlab - 512;
    }
  }

#pragma unroll
  for (int i = 0; i < NCHW; ++i) {
    gload_lds16(sp[i], L + dlo[i]);
    sp[i] += 512;
  }
  __syncthreads();

  for (int t = 0; t < 128; ++t) {
    u16* la = (t & 1) ? A1 : A0;
    u16* lb = (t & 1) ? B1 : B0;
    if (t < 127) {
      const int p = (t + 1) & 1;
#pragma unroll
      for (int i = 0; i < NCHW; ++i) {
        gload_lds16(sp[i], L + dlo[i] + (p ? dadd[i] : 0));
        sp[i] += p ? adv2[i] : 512;
      }
    }

    s16x8 ah[4], al[4], bh[NF], bl[NF];
#pragma unroll
    for (int mf = 0; mf < 4; ++mf)
      ah[mf] = *reinterpret_cast<const s16x8*>(&la[(wm4+mf)*512 + loff]);
#pragma unroll
    for (int nf = 0; nf < NF; ++nf)
      bh[nf] = *reinterpret_cast<const s16x8*>(&lb[(wnf+nf)*512 + loff]);
    __builtin_amdgcn_s_setprio(1);
#pragma unroll
    for (int nf = 0; nf < NF; ++nf)
#pragma unroll
      for (int mf = 0; mf < 4; ++mf)
        acc[mf][nf] = MFMA(ah[mf], bh[nf], acc[mf][nf]);
    __builtin_amdgcn_s_setprio(0);
#pragma unroll
    for (int mf = 0; mf < 4; ++mf)
      al[mf] = *reinterpret_cast<const s16x8*>(&la[4096 + (wm4+mf)*512 + loff]);
    __builtin_amdgcn_s_setprio(1);
#pragma unroll
    for (int nf = 0; nf < NF; ++nf)
#pragma unroll
      for (int mf = 0; mf < 4; ++mf)
        acc[mf][nf] = MFMA(al[mf], bh[nf], acc[mf][nf]);
    __builtin_amdgcn_s_setprio(0);
#pragma unroll
    for (int nf = 0; nf < NF; ++nf)
      bl[nf] = *reinterpret_cast<const s16x8*>(&lb[BNT*512 + (wnf+nf)*512 + loff]);
    __builtin_amdgcn_s_setprio(1);
#pragma unroll
    for (int nf = 0; nf < NF; ++nf)
#pragma unroll
      for (int mf = 0; mf < 4; ++mf)
        acc[mf][nf] = MFMA(ah[mf], bl[nf], acc[mf][nf]);
    __builtin_amdgcn_s_setprio(0);
    __syncthreads();
  }

  const int lg = lane >> 4, lr = lane & 15;
  const int rowb = mb*128 + (wid >> 2) * 64;
#pragma unroll
  for (int mf = 0; mf < 4; ++mf)
#pragma unroll
    for (int nf = 0; nf < NF; ++nf)
#pragma unroll
      for (int r = 0; r < 4; ++r) {
        int row = rowb + mf*16 + lg*4 + r;
        float v = acc[mf][nf][r];
        int gcol = nb*(NF*64) + (wid & 3)*(NF*16) + nf*16 + lr;
        if constexpr (RQ) {
          if (gcol < 4096)      C0[(size_t)row * 4096 + gcol] = v;
          else if (gcol < 5120) C1[(size_t)row * 1024 + (gcol - 4096)] = v;
          else                  C2[(size_t)row * 1024 + (gcol - 5120)] = v;
        } else {
          C0[(size_t)row * ldc0 + gcol] = v;
        }
      }
}

__global__ __launch_bounds__(512, 4) void gemm_qkv3(
    const u16* __restrict__ XAh, const u16* __restrict__ XAl,
    const u16* __restrict__ WBh, const u16* __restrict__ WBl,
    float* __restrict__ qb, float* __restrict__ kb, float* __restrict__ vb)
{
  __shared__ __attribute__((aligned(16))) u16 L[40960];
  int id = blockIdx.x;
  int xcd = id & 7, c = id >> 3;
  int nb = xcd * 4 + (c >> 4);
  int mb = c & 15;
  gemm128_core<3, true>(XAh, XAl, WBh, WBl, qb, kb, vb, 0, 384, mb, nb, L);
}

__global__ __launch_bounds__(512, 4) void gemm_out3(
    const u16* __restrict__ ABh, const u16* __restrict__ ABl,
    const u16* __restrict__ WOh, const u16* __restrict__ WOl,
    float* __restrict__ outp)
{
  __shared__ __attribute__((aligned(16))) u16 L[32768];
  int id = blockIdx.x;
  int xcd = id & 7, c = id >> 3;
  int nb = xcd * 4 + (c >> 4);
  int mb = c & 15;
  gemm128_core<2, false>(ABh, ABl, WOh, WOl, outp, nullptr, nullptr,
                         4096, 256, mb, nb, L);
}

// ===========================================================================
// attn3 (round-13 verified): fragment-staged flash attention, Q-RoPE fused.
// ===========================================================================
__global__ __launch_bounds__(512) void attn3(
    const float* __restrict__ qb,
    const float* __restrict__ cosT, const float* __restrict__ sinT,
    const u16* __restrict__ KFh, const u16* __restrict__ KFl,
    const u16* __restrict__ VFh, const u16* __restrict__ VFl,
    float* __restrict__ ob)
{
  __shared__ __attribute__((aligned(16))) u16 Klds[16384];
  __shared__ __attribute__((aligned(16))) u16 Vlds[16384];
  __shared__ u16 Ph[8][16][68], Pl[8][16][68];

  const int tid  = threadIdx.x;
  const int lane = tid & 63;
  const int wid  = tid >> 6;
  const int lr   = lane & 15;
  const int lg   = lane >> 4;
  const int loff = lane * 8;
  const int qt   = blockIdx.x;
  const int bh   = blockIdx.y;
  const int b    = bh >> 5, h = bh & 31;
  const int bkvh = b * 8 + (h >> 2);

  s16x8 qh[4], ql[4];
  {
    const int qrow = qt * 128 + wid * 16 + lr;
    const float* qp = qb + ((size_t)((b * S_ + qrow) * HQ_ + h)) * HD_;
    const float* cp = cosT + ((size_t)(b * S_ + qrow)) * HD_;
    const float* sp = sinT + ((size_t)(b * S_ + qrow)) * HD_;
#pragma unroll
    for (int kc = 0; kc < 4; ++kc) {
      const int d0 = kc * 32 + lg * 8;
      const float sgn = (d0 < 64) ? -1.f : 1.f;
      float4 v0 = *reinterpret_cast<const float4*>(qp + d0);
      float4 v1 = *reinterpret_cast<const float4*>(qp + d0 + 4);
      float4 p0 = *reinterpret_cast<const float4*>(qp + (d0 ^ 64));
      float4 p1 = *reinterpret_cast<const float4*>(qp + (d0 ^ 64) + 4);
      float4 c0 = *reinterpret_cast<const float4*>(cp + d0);
      float4 c1 = *reinterpret_cast<const float4*>(cp + d0 + 4);
      float4 s0 = *reinterpret_cast<const float4*>(sp + d0);
      float4 s1 = *reinterpret_cast<const float4*>(sp + d0 + 4);
      float4 r0, r1;
      r0.x = v0.x*c0.x + sgn*p0.x*s0.x;  r0.y = v0.y*c0.y + sgn*p0.y*s0.y;
      r0.z = v0.z*c0.z + sgn*p0.z*s0.z;  r0.w = v0.w*c0.w + sgn*p0.w*s0.w;
      r1.x = v1.x*c1.x + sgn*p1.x*s1.x;  r1.y = v1.y*c1.y + sgn*p1.y*s1.y;
      r1.z = v1.z*c1.z + sgn*p1.z*s1.z;  r1.w = v1.w*c1.w + sgn*p1.w*s1.w;
      uint4 h4, l4; pack8(r0, r1, h4, l4);
      qh[kc] = *reinterpret_cast<s16x8*>(&h4);
      ql[kc] = *reinterpret_cast<s16x8*>(&l4);
    }
  }

  f32x4 acc_o[8];
#pragma unroll
  for (int df = 0; df < 8; ++df) acc_o[df] = (f32x4){0.f, 0.f, 0.f, 0.f};
  float m_run[4] = {-1e30f, -1e30f, -1e30f, -1e30f};
  float l_run[4] = {0.f, 0.f, 0.f, 0.f};

  const u16* gKh = KFh + (size_t)bkvh * 131072;
  const u16* gKl = KFl + (size_t)bkvh * 131072;
  const u16* gVh = VFh + (size_t)bkvh * 131072;
  const u16* gVl = VFl + (size_t)bkvh * 131072;

#pragma unroll
  for (int i = 0; i < 4; ++i) {
    int idx = wid * 4 + i;
    const u16* src = (idx < 16) ? (gKh + idx*512) : (gKl + (idx-16)*512);
    u16* dst = Klds + ((idx < 16) ? idx*512 : 8192 + (idx-16)*512);
    gload_lds16(src + loff, dst);
  }
  __syncthreads();

  for (int t = 0; t < 16; ++t) {
#pragma unroll
    for (int i = 0; i < 4; ++i) {
      int idx = wid * 4 + i;
      const u16* src = (idx < 16) ? (gVh + t*8192 + idx*512)
                                  : (gVl + t*8192 + (idx-16)*512);
      u16* dst = Vlds + ((idx < 16) ? idx*512 : 8192 + (idx-16)*512);
      gload_lds16(src + loff, dst);
    }

    f32x4 accs[4];
#pragma unroll
    for (int nf = 0; nf < 4; ++nf) {
      accs[nf] = (f32x4){0.f, 0.f, 0.f, 0.f};
      s16x8 kh8[4], kl8[4];
#pragma unroll
      for (int kc = 0; kc < 4; ++kc) {
        kh8[kc] = *reinterpret_cast<const s16x8*>(&Klds[nf*2048 + kc*512 + loff]);
        kl8[kc] = *reinterpret_cast<const s16x8*>(&Klds[8192 + nf*2048 + kc*512 + loff]);
      }
#pragma unroll
      for (int kc = 0; kc < 4; ++kc) {
        accs[nf] = MFMA(qh[kc], kh8[kc], accs[nf]);
        accs[nf] = MFMA(ql[kc], kh8[kc], accs[nf]);
        accs[nf] = MFMA(qh[kc], kl8[kc], accs[nf]);
      }
    }
#pragma unroll
    for (int nf = 0; nf < 4; ++nf) accs[nf] *= SCALE_;

    float corr[4], rsum[4];
#pragma unroll
    for (int r = 0; r < 4; ++r) {
      float t0 = fmaxf(fmaxf(accs[0][r], accs[1][r]), fmaxf(accs[2][r], accs[3][r]));
      t0 = fmaxf(t0, __shfl_xor(t0, 1));
      t0 = fmaxf(t0, __shfl_xor(t0, 2));
      t0 = fmaxf(t0, __shfl_xor(t0, 4));
      t0 = fmaxf(t0, __shfl_xor(t0, 8));
      float mnew = fmaxf(m_run[r], t0);
      corr[r] = __expf(m_run[r] - mnew);
      m_run[r] = mnew;
      rsum[r] = 0.f;
    }
#pragma unroll
    for (int nf = 0; nf < 4; ++nf)
#pragma unroll
      for (int r = 0; r < 4; ++r) {
        float p = __expf(accs[nf][r] - m_run[r]);
        rsum[r] += p;
        u16 ph, pl;
        split2(p, ph, pl);
        Ph[wid][lg*4 + r][nf*16 + lr] = ph;
        Pl[wid][lg*4 + r][nf*16 + lr] = pl;
      }
#pragma unroll
    for (int r = 0; r < 4; ++r) {
      float s = rsum[r];
      s += __shfl_xor(s, 1); s += __shfl_xor(s, 2);
      s += __shfl_xor(s, 4); s += __shfl_xor(s, 8);
      l_run[r] = l_run[r] * corr[r] + s;
    }
#pragma unroll
    for (int df = 0; df < 8; ++df)
#pragma unroll
      for (int r = 0; r < 4; ++r) acc_o[df][r] *= corr[r];

    __syncthreads();

    if (t < 15) {
#pragma unroll
      for (int i = 0; i < 4; ++i) {
        int idx = wid * 4 + i;
        const u16* src = (idx < 16) ? (gKh + (t+1)*8192 + idx*512)
                                    : (gKl + (t+1)*8192 + (idx-16)*512);
        u16* dst = Klds + ((idx < 16) ? idx*512 : 8192 + (idx-16)*512);
        gload_lds16(src + loff, dst);
      }
    }

    s16x8 pa_h[2], pa_l[2];
#pragma unroll
    for (int kc = 0; kc < 2; ++kc) {
      pa_h[kc] = *reinterpret_cast<const s16x8*>(&Ph[wid][lr][kc*32 + lg*8]);
      pa_l[kc] = *reinterpret_cast<const s16x8*>(&Pl[wid][lr][kc*32 + lg*8]);
    }
#pragma unroll
    for (int df = 0; df < 8; ++df) {
      s16x8 vh8[2], vl8[2];
#pragma unroll
      for (int kc = 0; kc < 2; ++kc) {
        vh8[kc] = *reinterpret_cast<const s16x8*>(&Vlds[kc*4096 + df*512 + loff]);
        vl8[kc] = *reinterpret_cast<const s16x8*>(&Vlds[8192 + kc*4096 + df*512 + loff]);
      }
#pragma unroll
      for (int kc = 0; kc < 2; ++kc) {
        acc_o[df] = MFMA(pa_h[kc], vh8[kc], acc_o[df]);
        acc_o[df] = MFMA(pa_l[kc], vh8[kc], acc_o[df]);
        acc_o[df] = MFMA(pa_h[kc], vl8[kc], acc_o[df]);
      }
    }
    __syncthreads();
  }

  float inv_l[4];
#pragma unroll
  for (int r = 0; r < 4; ++r) inv_l[r] = 1.f / l_run[r];
#pragma unroll
  for (int df = 0; df < 8; ++df)
#pragma unroll
    for (int r = 0; r < 4; ++r) {
      int row = qt * 128 + wid * 16 + lg * 4 + r;
      ob[((size_t)((b * S_ + row) * HQ_ + h)) * HD_ + df*16 + lr] = acc_o[df][r] * inv_l[r];
    }
}

// ---------------------------------------------------------------------------
extern "C" void kernel_launch(void* const* d_in, const int* in_sizes, int n_in,
                              void* d_out, int out_size, void* d_ws, size_t ws_size,
                              hipStream_t stream)
{
  const float* hs   = (const float*)d_in[0];
  const float* cosT = (const float*)d_in[1];
  const float* sinT = (const float*)d_in[2];
  const float* Wq   = (const float*)d_in[3];
  const float* Wk   = (const float*)d_in[4];
  const float* Wv   = (const float*)d_in[5];
  const float* Wo   = (const float*)d_in[6];
  float* out = (float*)d_out;

  float* qb = (float*)d_ws;                 // 8388608 f32
  float* kb = qb + 8388608;                 // 2097152
  float* vb = kb + 2097152;                 // 2097152
  float* ab = vb + 2097152;                 // 8388608
  u16*   FR = (u16*)(ab + 8388608);

  u16* XAh = FR;
  u16* XAl = FR + 8388608;
  u16* WBh = FR + 16777216;
  u16* WBl = FR + 41943040;
  u16* KFh = FR + 16777216;
  u16* KFl = FR + 18874368;
  u16* VFh = FR + 20971520;
  u16* VFl = FR + 23068672;
  u16* WOh = FR + 25165824;
  u16* WOl = FR + 41943040;

  mega_frag1<<<13312, 256, 0, stream>>>(hs, Wq, Wk, Wv, XAh, XAl, WBh, WBl);
  gemm_qkv3<<<512, 512, 0, stream>>>(XAh, XAl, WBh, WBl, qb, kb, vb);
  mega_frag2<<<9216, 256, 0, stream>>>(kb, vb, cosT, sinT,
                                       KFh, KFl, VFh, VFl, Wo, WOh, WOl);
  attn3<<<dim3(8, 64), 512, 0, stream>>>(qb, cosT, sinT, KFh, KFl, VFh, VFl, ab);
  frag_a_k<<<dim3(64,16), 256, 0, stream>>>(ab, XAh, XAl);
  gemm_out3<<<512, 512, 0, stream>>>(XAh, XAl, WOh, WOl, out);
}